// Round 4
// baseline (1031.916 us; speedup 1.0000x reference)
//
#include <hip/hip_runtime.h>
#include <stdint.h>

typedef unsigned short u16;
typedef unsigned int   u32;
typedef unsigned long long u64;
typedef __attribute__((ext_vector_type(8))) short bf16x8;
typedef __attribute__((ext_vector_type(4))) float f32x4;

#define DEV static __device__ __forceinline__

DEV float b2f(u16 u){ u32 x = ((u32)u) << 16; float f; __builtin_memcpy(&f, &x, 4); return f; }
DEV u16 f2b(float f){ u32 x; __builtin_memcpy(&x, &f, 4); return (u16)((x + 0x7fffu + ((x >> 16) & 1u)) >> 16); }
DEV float ldf(const void* p, int i, int flg){
  return flg ? b2f(((const u16*)p)[i]) : ((const float*)p)[i];
}

// Dims: B=4, H=W=64, HW=4096, Cin=512, Cm=128, Ck=16, Cout=64
// Padded pixel space: 66x66 = 4356, interior pixel (h,w) -> h*66+w+67
static constexpr int HW   = 4096;
static constexpr int PPIX = 4356;

// ---------------------------------------------------------------------------
__global__ void k_detect(const u32* __restrict__ x, int* __restrict__ flag)
{
  __shared__ int cnt;
  if (threadIdx.x == 0) cnt = 0;
  __syncthreads();
  const u32 w  = x[threadIdx.x];
  const u32 eb = (w >> 7) & 0xFFu;
  if (eb >= 100u && eb <= 150u) atomicAdd(&cnt, 1);
  __syncthreads();
  if (threadIdx.x == 0) *flag = (cnt > 384) ? 1 : 0;
}

// ---------------------------------------------------------------------------
__global__ void k_cvt(const void* __restrict__ src, const int* __restrict__ flagp,
                      u16* __restrict__ dst, int n)
{
  const int i = (blockIdx.x * 256 + threadIdx.x) << 2;
  if (i >= n) return;
  u64 ov;
  if (*flagp){
    ov = ((const u64*)src)[i >> 2];
  } else {
    const float4 f = ((const float4*)src)[i >> 2];
    const u16 a0 = f2b(f.x), a1 = f2b(f.y), a2 = f2b(f.z), a3 = f2b(f.w);
    ov = (u64)a0 | ((u64)a1 << 16) | ((u64)a2 << 32) | ((u64)a3 << 48);
  }
  ((u64*)dst)[i >> 2] = ov;
}

// ---------------------------------------------------------------------------
__global__ void k_prep(
    const void* g0,const void* b0,const void* m0,const void* v0,
    const void* g1,const void* b1,const void* m1,const void* v1,
    const void* g2,const void* b2,const void* m2,const void* v2,
    const void* g3,const void* b3,const void* m3,const void* v3,
    const int* __restrict__ flagp, float* scale, float* shift)
{
  const int t = threadIdx.x;
  if (t >= 512) return;
  const int flg = *flagp;
  const int set = t >> 7, c = t & 127;
  const void *gp,*bp,*mp,*vp;
  if      (set == 0){gp=g0;bp=b0;mp=m0;vp=v0;}
  else if (set == 1){gp=g1;bp=b1;mp=m1;vp=v1;}
  else if (set == 2){gp=g2;bp=b2;mp=m2;vp=v2;}
  else              {gp=g3;bp=b3;mp=m3;vp=v3;}
  const float sc = ldf(gp,c,flg) * rsqrtf(ldf(vp,c,flg) + 1e-5f);
  scale[t] = sc;
  shift[t] = ldf(bp,c,flg) - ldf(mp,c,flg) * sc;
}

// ---------------------------------------------------------------------------
// Weight reorder+convert for 3x3 convs: [co][ci][rs] -> bf16 [co][rs][ci]
// ---------------------------------------------------------------------------
__global__ void k_reorder_cvt(const void* __restrict__ win, const int* __restrict__ flagp,
                              u16* __restrict__ wout, int cin)
{
  const int idx = blockIdx.x * 256 + threadIdx.x;
  const int flg = *flagp;
  const int n9 = cin * 9;
  const int co = idx / n9;
  const int rem = idx - co * n9;
  const int ci = rem / 9;
  const int rs = rem - ci * 9;
  const u16 v = flg ? ((const u16*)win)[idx] : f2b(((const float*)win)[idx]);
  wout[co * n9 + rs * cin + ci] = v;
}

// ---------------------------------------------------------------------------
// Zero the 1-pixel halo of a padded pixel-major tensor [4][4356][C_]
// 260 halo pixels per batch; 16B per thread.
// ---------------------------------------------------------------------------
template<int C_>
__global__ void k_halo(u16* __restrict__ buf)
{
  const int tid = blockIdx.x * 256 + threadIdx.x;
  const int e  = tid * 8;
  const int cc = e % C_;
  int rem = e / C_;
  const int hp = rem % 260;
  const int b  = rem / 260;
  int pix;
  if      (hp < 66)  pix = hp;
  else if (hp < 132) pix = 65 * 66 + (hp - 66);
  else if (hp < 196) pix = (hp - 132 + 1) * 66;
  else               pix = (hp - 196 + 1) * 66 + 65;
  uint4 z; z.x = 0; z.y = 0; z.z = 0; z.w = 0;
  *(uint4*)(buf + ((size_t)b * PPIX + pix) * C_ + cc) = z;
}

// ---------------------------------------------------------------------------
// x transpose: [b][512][4096] (fp32 or bf16) -> padded bf16 [b][4356][512]
// Wave: 64 c (lanes) x 32 p. Block 4 waves. Grid = 4b x 8ct x 32pb = 1024.
// ---------------------------------------------------------------------------
__global__ __launch_bounds__(256) void k_xT(
    const void* __restrict__ src, const int* __restrict__ flagp, u16* __restrict__ dst)
{
  const int t = threadIdx.x, wave = t >> 6, lane = t & 63;
  const int pb = blockIdx.x & 31, ct = (blockIdx.x >> 5) & 7, b = blockIdx.x >> 8;
  const int c  = ct * 64 + lane;
  const int p0 = pb * 128 + wave * 32;
  const size_t sbase = ((size_t)(b * 512) + c) * 4096 + p0;

  u16 vals[32];
  if (*flagp){
    const u16* s = (const u16*)src + sbase;
    #pragma unroll
    for (int k = 0; k < 4; ++k){
      uint4 v = *(const uint4*)(s + k * 8);
      __builtin_memcpy(&vals[k * 8], &v, 16);
    }
  } else {
    const float* s = (const float*)src + sbase;
    #pragma unroll
    for (int k = 0; k < 8; ++k){
      float4 v = *(const float4*)(s + k * 4);
      vals[k*4+0] = f2b(v.x); vals[k*4+1] = f2b(v.y);
      vals[k*4+2] = f2b(v.z); vals[k*4+3] = f2b(v.w);
    }
  }
  const int hrow = (p0 >> 6) * 66 + (p0 & 63) + 67;   // p0..p0+31 same h row
  u16* d = dst + ((size_t)b * PPIX + hrow) * 512 + c;
  #pragma unroll
  for (int k = 0; k < 32; ++k) d[(size_t)k * 512] = vals[k];
}

// ---------------------------------------------------------------------------
// Implicit-GEMM conv, pixel-major input [b][IPIX][CIN], MFMA 16x16x32 bf16.
// One wave per 16(co) x 16(px) tile; A and B frags are single 16B loads.
// EPI: 0 = BN+ReLU -> pixel-major bf16 (8B store/lane)
//      5 = EPI0 + dual channel-major store (outB2)
//      2 = +bias -> channel-major bf16
//      3 = +bias -> flag ? bf16 : fp32, channel-major (d_out heads)
//      4 = +bias -> qT hi/lo bf16 pair [b][4096][16]
// ---------------------------------------------------------------------------
template<int CIN_, int KH_, int CO_, int EPI_, bool SUM2_, bool PADIN_, bool PADOUT_>
__global__ __launch_bounds__(256) void k_convT(
    const u16* __restrict__ xin, const u16* __restrict__ xin2,
    const u16* __restrict__ wK,
    const float* __restrict__ scale, const float* __restrict__ shift,
    const void* __restrict__ bias, const int* __restrict__ flagp,
    u16* __restrict__ outB, float* __restrict__ outF, u16* __restrict__ outB2)
{
  constexpr int K    = CIN_ * KH_ * KH_;
  constexpr int MT   = CO_ / 16;
  constexpr int IPIX = PADIN_ ? PPIX : 4096;
  constexpr int OPIX = PADOUT_ ? PPIX : 4096;

  const int tid  = threadIdx.x;
  const int wave = tid >> 6;
  const int lane = tid & 63;
  const int l16  = lane & 15;
  const int quad = lane >> 4;

  int tile = blockIdx.x * 4 + wave;
  const int nt = tile & 255; tile >>= 8;
  const int mt = tile % MT;
  const int b  = tile / MT;

  const int p = nt * 16 + l16;
  const int h = p >> 6, wc = p & 63;

  const u16* wrow = wK + (size_t)(mt * 16 + l16) * K + quad * 8;
  const u16* xb   = xin + (size_t)b * IPIX * CIN_ + quad * 8;

  f32x4 acc = {0.f, 0.f, 0.f, 0.f};

  if constexpr (KH_ == 3){
    #pragma unroll 1
    for (int r = 0; r < 3; ++r){
      #pragma unroll
      for (int s = 0; s < 3; ++s){
        const u16* xrs = xb + (size_t)((h + r) * 66 + wc + s) * CIN_;
        const u16* wrs = wrow + (r * 3 + s) * CIN_;
        #pragma unroll
        for (int ci0 = 0; ci0 < CIN_; ci0 += 32){
          bf16x8 af = *(const bf16x8*)(wrs + ci0);
          bf16x8 bf = *(const bf16x8*)(xrs + ci0);
          acc = __builtin_amdgcn_mfma_f32_16x16x32_bf16(af, bf, acc, 0, 0, 0);
        }
      }
    }
  } else {
    const int poff = PADIN_ ? (h * 66 + wc + 67) : p;
    const u16* xrs = xb + (size_t)poff * CIN_;
    const u16* xrs2 = nullptr;
    if constexpr (SUM2_) xrs2 = xin2 + (size_t)b * IPIX * CIN_ + quad * 8 + (size_t)poff * CIN_;
    #pragma unroll
    for (int ci0 = 0; ci0 < CIN_; ci0 += 32){
      bf16x8 af = *(const bf16x8*)(wrow + ci0);
      bf16x8 bf;
      if constexpr (SUM2_){
        bf16x8 b1 = *(const bf16x8*)(xrs + ci0);
        bf16x8 b2 = *(const bf16x8*)(xrs2 + ci0);
        #pragma unroll
        for (int j = 0; j < 8; ++j)
          bf[j] = (short)f2b(b2f((u16)b1[j]) + b2f((u16)b2[j]));
      } else {
        bf = *(const bf16x8*)(xrs + ci0);
      }
      acc = __builtin_amdgcn_mfma_f32_16x16x32_bf16(af, bf, acc, 0, 0, 0);
    }
  }

  int flg = 0;
  if constexpr (EPI_ == 2 || EPI_ == 3 || EPI_ == 4) flg = *flagp;

  if constexpr (EPI_ == 0 || EPI_ == 5){
    u16 pk[4];
    #pragma unroll
    for (int rr = 0; rr < 4; ++rr){
      const int co = mt * 16 + quad * 4 + rr;
      pk[rr] = f2b(fmaxf(acc[rr] * scale[co] + shift[co], 0.f));
    }
    const int opix = PADOUT_ ? (h * 66 + wc + 67) : p;
    u64 pkv; __builtin_memcpy(&pkv, pk, 8);
    *(u64*)(outB + ((size_t)b * OPIX + opix) * CO_ + mt * 16 + quad * 4) = pkv;
    if constexpr (EPI_ == 5){
      #pragma unroll
      for (int rr = 0; rr < 4; ++rr){
        const int co = mt * 16 + quad * 4 + rr;
        outB2[((size_t)(b * CO_) + co) * 4096 + p] = pk[rr];
      }
    }
  } else if constexpr (EPI_ == 4){
    #pragma unroll
    for (int rr = 0; rr < 4; ++rr){
      const int co = quad * 4 + rr;   // MT == 1
      const float vv = acc[rr] + ldf(bias, co, flg);
      const u16 hb = f2b(vv);
      const float lo = vv - b2f(hb);
      const size_t qaddr = ((size_t)b * 4096 + p) * 16 + co;
      outB[qaddr] = hb;
      ((u16*)outF)[qaddr] = f2b(lo);
    }
  } else {
    #pragma unroll
    for (int rr = 0; rr < 4; ++rr){
      const int co = mt * 16 + quad * 4 + rr;
      const float vv = acc[rr] + ldf(bias, co, flg);
      const size_t addr = ((size_t)(b * CO_) + co) * 4096 + p;
      if constexpr (EPI_ == 2) outB[addr] = f2b(vv);
      else { if (flg) outB[addr] = f2b(vv); else outF[addr] = vv; }
    }
  }
}

// ---------------------------------------------------------------------------
// PAM flash attention (unchanged from R3): grid 1024 = b x 64 i-tile x 4 j-seg.
// ---------------------------------------------------------------------------
__global__ __launch_bounds__(256) void k_pam_flash(
    const u16* __restrict__ qTh, const u16* __restrict__ qTl,
    const u16* __restrict__ v,
    u16* __restrict__ po, float* __restrict__ pm, float* __restrict__ pl)
{
  __shared__ u16 vls[128 * 72];
  __shared__ u16 pls[64 * 72];

  const int t    = threadIdx.x;
  const int wave = t >> 6, lane = t & 63;
  const int l16  = lane & 15, quad = lane >> 4;

  const int bid = blockIdx.x;
  const int js  = bid & 3, it = (bid >> 2) & 63, b = bid >> 8;
  const int i0  = it * 64;
  const int jbase = js * 1024;

  const u16* qTbh = qTh + ((size_t)b * 4096) * 16;
  const u16* qTbl = qTl + ((size_t)b * 4096) * 16;
  const u16* vb   = v + ((size_t)b * 128) * 4096;

  bf16x8 afh = {}, afl = {};
  {
    const int i = i0 + wave * 16 + l16;
    if (quad < 2){
      *(uint4*)&afh = *(const uint4*)(qTbh + (size_t)i * 16 + quad * 8);
      *(uint4*)&afl = *(const uint4*)(qTbl + (size_t)i * 16 + quad * 8);
    }
  }

  f32x4 oacc[8];
  #pragma unroll
  for (int cs = 0; cs < 8; ++cs){ oacc[cs][0]=0.f; oacc[cs][1]=0.f; oacc[cs][2]=0.f; oacc[cs][3]=0.f; }
  float m_run[4], l_run[4];
  #pragma unroll
  for (int r = 0; r < 4; ++r){ m_run[r] = -1e30f; l_run[r] = 0.f; }

  const int vc = t >> 1, vjh = (t & 1) * 32;

  for (int ch = 0; ch < 16; ++ch){
    const int j0 = jbase + ch * 64;
    __syncthreads();
    {
      const u16* src = vb + (size_t)vc * 4096 + j0 + vjh;
      u16* dst = vls + vc * 72 + vjh;
      *(uint4*)(dst)      = *(const uint4*)(src);
      *(uint4*)(dst + 8)  = *(const uint4*)(src + 8);
      *(uint4*)(dst + 16) = *(const uint4*)(src + 16);
      *(uint4*)(dst + 24) = *(const uint4*)(src + 24);
    }
    f32x4 sacc[4];
    #pragma unroll
    for (int ns = 0; ns < 4; ++ns){
      bf16x8 bh = {}, bl = {};
      const int j = j0 + ns * 16 + l16;
      if (quad < 2){
        *(uint4*)&bh = *(const uint4*)(qTbh + (size_t)j * 16 + quad * 8);
        *(uint4*)&bl = *(const uint4*)(qTbl + (size_t)j * 16 + quad * 8);
      }
      f32x4 z = {0.f, 0.f, 0.f, 0.f};
      z = __builtin_amdgcn_mfma_f32_16x16x32_bf16(afh, bh, z, 0, 0, 0);
      z = __builtin_amdgcn_mfma_f32_16x16x32_bf16(afh, bl, z, 0, 0, 0);
      z = __builtin_amdgcn_mfma_f32_16x16x32_bf16(afl, bh, z, 0, 0, 0);
      sacc[ns] = z;
    }
    float pv[4][4];
    #pragma unroll
    for (int r = 0; r < 4; ++r){
      float mx = fmaxf(fmaxf(sacc[0][r], sacc[1][r]), fmaxf(sacc[2][r], sacc[3][r]));
      mx = fmaxf(mx, __shfl_xor(mx, 1));
      mx = fmaxf(mx, __shfl_xor(mx, 2));
      mx = fmaxf(mx, __shfl_xor(mx, 4));
      mx = fmaxf(mx, __shfl_xor(mx, 8));
      const float mnew  = fmaxf(m_run[r], mx);
      const float alpha = __expf(m_run[r] - mnew);
      m_run[r] = mnew;
      float rs = 0.f;
      #pragma unroll
      for (int ns = 0; ns < 4; ++ns){
        pv[ns][r] = __expf(sacc[ns][r] - mnew);
        rs += pv[ns][r];
      }
      rs += __shfl_xor(rs, 1); rs += __shfl_xor(rs, 2);
      rs += __shfl_xor(rs, 4); rs += __shfl_xor(rs, 8);
      l_run[r] = l_run[r] * alpha + rs;
      #pragma unroll
      for (int cs = 0; cs < 8; ++cs) oacc[cs][r] *= alpha;
    }
    #pragma unroll
    for (int r = 0; r < 4; ++r)
      #pragma unroll
      for (int ns = 0; ns < 4; ++ns)
        pls[(wave * 16 + quad * 4 + r) * 72 + ns * 16 + l16] = f2b(pv[ns][r]);
    __syncthreads();
    #pragma unroll
    for (int ks = 0; ks < 2; ++ks){
      bf16x8 pf = *(const bf16x8*)(pls + (wave * 16 + l16) * 72 + ks * 32 + quad * 8);
      #pragma unroll
      for (int cs = 0; cs < 8; ++cs){
        bf16x8 vf = *(const bf16x8*)(vls + (cs * 16 + l16) * 72 + ks * 32 + quad * 8);
        oacc[cs] = __builtin_amdgcn_mfma_f32_16x16x32_bf16(pf, vf, oacc[cs], 0, 0, 0);
      }
    }
  }

  u16* pob = po + (size_t)bid * 64 * 128;
  #pragma unroll
  for (int cs = 0; cs < 8; ++cs)
    #pragma unroll
    for (int r = 0; r < 4; ++r)
      pob[(wave * 16 + quad * 4 + r) * 128 + cs * 16 + l16] = f2b(oacc[cs][r]);
  if (l16 == 0){
    #pragma unroll
    for (int r = 0; r < 4; ++r){
      pm[(size_t)bid * 64 + wave * 16 + quad * 4 + r] = m_run[r];
      pl[(size_t)bid * 64 + wave * 16 + quad * 4 + r] = l_run[r];
    }
  }
}

// ---------------------------------------------------------------------------
// PAM combine (pixel-major): merge 4 j-seg partials, gamma + residual,
// in-place over padded feat1_T. Grid 256 = b(4) x i-tile(64).
// ---------------------------------------------------------------------------
__global__ __launch_bounds__(256) void k_pam_comb2(
    const u16* __restrict__ po, const float* __restrict__ pm, const float* __restrict__ pl,
    const void* __restrict__ gptr, const int* __restrict__ flagp,
    u16* __restrict__ featT)
{
  __shared__ float wgt[4][64];
  const int t  = threadIdx.x;
  const int it = blockIdx.x & 63, b = blockIdx.x >> 6;
  const int base = (b * 64 + it) * 4;
  if (t < 64){
    const float m0 = pm[(size_t)(base+0)*64 + t];
    const float m1 = pm[(size_t)(base+1)*64 + t];
    const float m2 = pm[(size_t)(base+2)*64 + t];
    const float m3 = pm[(size_t)(base+3)*64 + t];
    const float M  = fmaxf(fmaxf(m0, m1), fmaxf(m2, m3));
    const float e0 = __expf(m0 - M), e1 = __expf(m1 - M);
    const float e2 = __expf(m2 - M), e3 = __expf(m3 - M);
    const float L  = pl[(size_t)(base+0)*64+t]*e0 + pl[(size_t)(base+1)*64+t]*e1
                   + pl[(size_t)(base+2)*64+t]*e2 + pl[(size_t)(base+3)*64+t]*e3;
    const float li = 1.0f / L;
    wgt[0][t] = e0*li; wgt[1][t] = e1*li; wgt[2][t] = e2*li; wgt[3][t] = e3*li;
  }
  __syncthreads();
  const float g = ldf(gptr, 0, *flagp);
  const int c = t & 127, ih = t >> 7;
  const int i0 = it * 64;
  for (int st = 0; st < 32; ++st){
    const int il = ih + st * 2;
    float acc = 0.f;
    #pragma unroll
    for (int s = 0; s < 4; ++s)
      acc += wgt[s][il] * b2f(po[((size_t)(base+s)*64 + il)*128 + c]);
    const int i = i0 + il;
    const int pix = (i >> 6) * 66 + (i & 63) + 67;
    u16* addr = featT + ((size_t)b * PPIX + pix) * 128 + c;
    *addr = f2b(g * acc + b2f(*addr));
  }
}

// ---------------------------------------------------------------------------
// CAM attention (channel-major feat2): writes attn^T bf16 [b][d][c].
// ---------------------------------------------------------------------------
__global__ __launch_bounds__(128) void k_cam_attn(
    const u16* __restrict__ f, u16* __restrict__ attnT)
{
  __shared__ float fc[4096];
  __shared__ float red[128];
  const int d = threadIdx.x;
  const int c = blockIdx.x & 127, b = blockIdx.x >> 7;
  const u16* fb   = f + (size_t)b * 128 * HW;
  const u16* rowc = fb + (size_t)c * HW;
  for (int mi = d; mi < 4096; mi += 128) fc[mi] = b2f(rowc[mi]);
  __syncthreads();

  const u16* rowd = fb + (size_t)d * HW;
  float e = 0.f;
  for (int mm = 0; mm < 4096; mm += 8){
    const uint4 xv = *(const uint4*)(rowd + mm);
    const u16* px = (const u16*)&xv;
    #pragma unroll
    for (int k = 0; k < 8; ++k) e += fc[mm + k] * b2f(px[k]);
  }
  red[d] = e;
  __syncthreads();
  for (int st = 64; st > 0; st >>= 1){
    if (d < st) red[d] = fminf(red[d], red[d + st]);
    __syncthreads();
  }
  const float emin = red[0];
  __syncthreads();
  const float pd = __expf(emin - e);
  red[d] = pd;
  __syncthreads();
  for (int st = 64; st > 0; st >>= 1){
    if (d < st) red[d] += red[d + st];
    __syncthreads();
  }
  attnT[((size_t)b * 128 + d) * 128 + c] = f2b(pd / red[0]);
}

// ---------------------------------------------------------------------------
// CAM output: cafeat_T[m][c] = gamma * sum_d attnT[d][c] f_cm[d][m] + f_T[m][c]
// Block: 16 m x 128 c; thread (c, mg) handles 8 m. Grid 1024 = b x 256.
// f-row loads are wave-broadcast (all lanes same address).
// ---------------------------------------------------------------------------
__global__ __launch_bounds__(256) void k_cam_out2(
    const u16* __restrict__ fcm, const u16* __restrict__ fT,
    const u16* __restrict__ attnT, const void* __restrict__ gptr,
    const int* __restrict__ flagp, u16* __restrict__ outT)
{
  __shared__ u16 als[128 * 128];
  const int t = threadIdx.x;
  const int b = blockIdx.x >> 8, m0 = (blockIdx.x & 255) * 16;
  {
    const uint4* src = (const uint4*)(attnT + (size_t)b * 128 * 128);
    uint4* dstl = (uint4*)als;
    #pragma unroll
    for (int k = 0; k < 8; ++k) dstl[t + k * 256] = src[t + k * 256];
  }
  __syncthreads();
  const int c = t & 127, mg = t >> 7;
  const int m = m0 + mg * 8;
  const u16* frow = fcm + (size_t)b * 128 * HW + m;
  float acc[8];
  #pragma unroll
  for (int k = 0; k < 8; ++k) acc[k] = 0.f;
  for (int d = 0; d < 128; ++d){
    const float ad = b2f(als[d * 128 + c]);
    const uint4 fv = *(const uint4*)(frow + (size_t)d * HW);
    const u16* pf = (const u16*)&fv;
    #pragma unroll
    for (int k = 0; k < 8; ++k) acc[k] += ad * b2f(pf[k]);
  }
  const float g = ldf(gptr, 0, *flagp);
  const int hrow = (m >> 6) * 66 + (m & 63) + 67;   // m..m+7 same row
  #pragma unroll
  for (int k = 0; k < 8; ++k){
    const size_t addr = ((size_t)b * PPIX + hrow + k) * 128 + c;
    outT[addr] = f2b(g * acc[k] + b2f(fT[addr]));
  }
}

// ---------------------------------------------------------------------------
extern "C" void kernel_launch(void* const* d_in, const int* in_sizes, int n_in,
                              void* d_out, int out_size, void* d_ws, size_t ws_size,
                              hipStream_t stream)
{
  (void)in_sizes; (void)n_in; (void)out_size; (void)ws_size;

  const void* x    = d_in[0];
  const void* w11  = d_in[1];
  const void* g11  = d_in[2];
  const void* b11  = d_in[3];
  const void* m11  = d_in[4];
  const void* v11  = d_in[5];
  const void* w12  = d_in[6];
  const void* g12  = d_in[7];
  const void* b12  = d_in[8];
  const void* m12  = d_in[9];
  const void* v12  = d_in[10];
  const void* kw   = d_in[11];
  const void* kb   = d_in[12];
  const void* vw   = d_in[13];
  const void* vb   = d_in[14];
  const void* pgam = d_in[15];
  const void* cgam = d_in[16];
  const void* w21  = d_in[17];
  const void* g21  = d_in[18];
  const void* b21  = d_in[19];
  const void* m21  = d_in[20];
  const void* v21  = d_in[21];
  const void* w22  = d_in[22];
  const void* g22  = d_in[23];
  const void* b22  = d_in[24];
  const void* m22  = d_in[25];
  const void* v22  = d_in[26];
  const void* w31  = d_in[27];
  const void* b31  = d_in[28];
  const void* w32  = d_in[29];
  const void* b32  = d_in[30];
  const void* w4   = d_in[31];
  const void* b4   = d_in[32];

  char* wsb = (char*)d_ws;
  size_t off = 0;
  auto alloc = [&](size_t bytes) -> void* {
    void* pp = wsb + off;
    off += (bytes + 255) & ~(size_t)255;
    return pp;
  };
  u16*   xT      = (u16*)alloc((size_t)4 * PPIX * 512 * 2);  // dead after trunk -> po
  u16*   feat1T  = (u16*)alloc((size_t)4 * PPIX * 128 * 2);  // padded; later pa_feat (in-place)
  u16*   feat2T  = (u16*)alloc((size_t)4 * PPIX * 128 * 2);  // padded (residual reads)
  u16*   feat2cm = (u16*)alloc((size_t)4 * 128 * HW * 2);    // channel-major (CAM)
  u16*   cafeatT = (u16*)alloc((size_t)4 * PPIX * 128 * 2);  // padded
  u16*   vbuf    = (u16*)alloc((size_t)4 * 128 * HW * 2);    // v cm; later pa_conv_T (unpadded)
  u16*   caconvT = (u16*)alloc((size_t)4 * HW * 128 * 2);    // unpadded pixel-major
  u16*   qTh     = (u16*)alloc((size_t)4 * HW * 16 * 2);
  u16*   qTl     = (u16*)alloc((size_t)4 * HW * 16 * 2);
  float* pm      = (float*)alloc((size_t)1024 * 64 * 4);
  float* pl      = (float*)alloc((size_t)1024 * 64 * 4);
  u16*   attnT   = (u16*)alloc((size_t)4 * 128 * 128 * 2);
  float* scale   = (float*)alloc(512 * 4);
  float* shift   = (float*)alloc(512 * 4);
  u16*   w11r    = (u16*)alloc((size_t)128 * 4608 * 2);
  u16*   w12r    = (u16*)alloc((size_t)128 * 4608 * 2);
  u16*   w21r    = (u16*)alloc((size_t)128 * 1152 * 2);
  u16*   w22r    = (u16*)alloc((size_t)128 * 1152 * 2);
  u16*   kwb     = (u16*)alloc((size_t)16 * 128 * 2);
  u16*   vwb     = (u16*)alloc((size_t)128 * 128 * 2);
  u16*   w31b    = (u16*)alloc((size_t)64 * 128 * 2);
  u16*   w32b    = (u16*)alloc((size_t)64 * 128 * 2);
  u16*   w4b     = (u16*)alloc((size_t)64 * 128 * 2);
  int*   flag    = (int*)alloc(256);
  u16*   po      = xT;   // 1024*64*128*2 = 16.8 MB <= xT's 17.8 MB; xT dead by then

  // prep: dtype flag, BN fold, halo zero, transpose, weight conversion
  k_detect<<<1, 512, 0, stream>>>((const u32*)x, flag);
  k_prep<<<1, 512, 0, stream>>>(g11,b11,m11,v11, g12,b12,m12,v12,
                                g21,b21,m21,v21, g22,b22,m22,v22, flag, scale, shift);
  k_halo<512><<<260, 256, 0, stream>>>(xT);
  k_halo<128><<<65, 256, 0, stream>>>(feat1T);
  k_halo<128><<<65, 256, 0, stream>>>(cafeatT);
  k_xT<<<1024, 256, 0, stream>>>(x, flag, xT);
  k_reorder_cvt<<<2304, 256, 0, stream>>>(w11, flag, w11r, 512);
  k_reorder_cvt<<<2304, 256, 0, stream>>>(w12, flag, w12r, 512);
  k_reorder_cvt<<<576, 256, 0, stream>>>(w21, flag, w21r, 128);
  k_reorder_cvt<<<576, 256, 0, stream>>>(w22, flag, w22r, 128);
  k_cvt<<<2, 256, 0, stream>>>(kw, flag, kwb, 16 * 128);
  k_cvt<<<16, 256, 0, stream>>>(vw, flag, vwb, 128 * 128);
  k_cvt<<<8, 256, 0, stream>>>(w31, flag, w31b, 64 * 128);
  k_cvt<<<8, 256, 0, stream>>>(w32, flag, w32b, 64 * 128);
  k_cvt<<<8, 256, 0, stream>>>(w4, flag, w4b, 64 * 128);

  // trunk convs (pixel-major in/out)
  k_convT<512,3,128,0,false,true,true><<<2048,256,0,stream>>>(
      xT, nullptr, w11r, scale,       shift,       nullptr, flag, feat1T, nullptr, nullptr);
  k_convT<512,3,128,5,false,true,true><<<2048,256,0,stream>>>(
      xT, nullptr, w12r, scale + 128, shift + 128, nullptr, flag, feat2T, nullptr, feat2cm);

  // PAM
  k_convT<128,1,16,4,false,true,false><<<256,256,0,stream>>>(
      feat1T, nullptr, kwb, nullptr, nullptr, kb, flag, qTh, (float*)qTl, nullptr);
  k_convT<128,1,128,2,false,true,false><<<2048,256,0,stream>>>(
      feat1T, nullptr, vwb, nullptr, nullptr, vb, flag, vbuf, nullptr, nullptr);
  k_pam_flash<<<1024, 256, 0, stream>>>(qTh, qTl, vbuf, po, pm, pl);
  k_pam_comb2<<<256, 256, 0, stream>>>(po, pm, pl, pgam, flag, feat1T);  // -> pa_feat in-place

  // CAM
  k_cam_attn<<<512, 128, 0, stream>>>(feat2cm, attnT);
  k_cam_out2<<<1024, 256, 0, stream>>>(feat2cm, feat2T, attnT, cgam, flag, cafeatT);

  // second convs (padded in, unpadded pixel-major out)
  k_convT<128,3,128,0,false,true,false><<<2048,256,0,stream>>>(
      feat1T,  nullptr, w21r, scale + 256, shift + 256, nullptr, flag, vbuf,    nullptr, nullptr);
  k_convT<128,3,128,0,false,true,false><<<2048,256,0,stream>>>(
      cafeatT, nullptr, w22r, scale + 384, shift + 384, nullptr, flag, caconvT, nullptr, nullptr);

  // heads -> d_out [3][4][64][4096], channel-major, dtype per flag
  const size_t SEC = (size_t)4 * 64 * HW;
  u16*   outB = (u16*)d_out;
  float* outF = (float*)d_out;
  k_convT<128,1,64,3,false,false,false><<<1024,256,0,stream>>>(
      vbuf,    nullptr, w31b, nullptr, nullptr, b31, flag, outB,           outF,           nullptr);
  k_convT<128,1,64,3,false,false,false><<<1024,256,0,stream>>>(
      caconvT, nullptr, w32b, nullptr, nullptr, b32, flag, outB + SEC,     outF + SEC,     nullptr);
  k_convT<128,1,64,3,true ,false,false><<<1024,256,0,stream>>>(
      vbuf,    caconvT, w4b,  nullptr, nullptr, b4,  flag, outB + 2 * SEC, outF + 2 * SEC, nullptr);
}

// Round 5
// 497.195 us; speedup vs baseline: 2.0755x; 2.0755x over previous
//
#include <hip/hip_runtime.h>
#include <stdint.h>

typedef unsigned short u16;
typedef unsigned int   u32;
typedef unsigned long long u64;
typedef __attribute__((ext_vector_type(8))) short bf16x8;
typedef __attribute__((ext_vector_type(4))) float f32x4;

#define DEV static __device__ __forceinline__

DEV float b2f(u16 u){ u32 x = ((u32)u) << 16; float f; __builtin_memcpy(&f, &x, 4); return f; }
DEV u16 f2b(float f){ u32 x; __builtin_memcpy(&x, &f, 4); return (u16)((x + 0x7fffu + ((x >> 16) & 1u)) >> 16); }
DEV float ldf(const void* p, int i, int flg){
  return flg ? b2f(((const u16*)p)[i]) : ((const float*)p)[i];
}
// async global->LDS, 16B per lane; LDS dest = wave-uniform base + lane*16
DEV void gload_lds16(const u16* g, u16* l){
  __builtin_amdgcn_global_load_lds((const __attribute__((address_space(1))) void*)g,
                                   (__attribute__((address_space(3))) void*)l, 16, 0, 0);
}

// Dims: B=4, H=W=64, HW=4096, Cin=512, Cm=128, Ck=16, Cout=64
// Padded pixel space: 66x66 = 4356, interior pixel (h,w) -> h*66+w+67
static constexpr int HW   = 4096;
static constexpr int PPIX = 4356;

// ---------------------------------------------------------------------------
__global__ void k_detect(const u32* __restrict__ x, int* __restrict__ flag)
{
  __shared__ int cnt;
  if (threadIdx.x == 0) cnt = 0;
  __syncthreads();
  const u32 w  = x[threadIdx.x];
  const u32 eb = (w >> 7) & 0xFFu;
  if (eb >= 100u && eb <= 150u) atomicAdd(&cnt, 1);
  __syncthreads();
  if (threadIdx.x == 0) *flag = (cnt > 384) ? 1 : 0;
}

// ---------------------------------------------------------------------------
__global__ void k_cvt(const void* __restrict__ src, const int* __restrict__ flagp,
                      u16* __restrict__ dst, int n)
{
  const int i = (blockIdx.x * 256 + threadIdx.x) << 2;
  if (i >= n) return;
  u64 ov;
  if (*flagp){
    ov = ((const u64*)src)[i >> 2];
  } else {
    const float4 f = ((const float4*)src)[i >> 2];
    const u16 a0 = f2b(f.x), a1 = f2b(f.y), a2 = f2b(f.z), a3 = f2b(f.w);
    ov = (u64)a0 | ((u64)a1 << 16) | ((u64)a2 << 32) | ((u64)a3 << 48);
  }
  ((u64*)dst)[i >> 2] = ov;
}

// ---------------------------------------------------------------------------
__global__ void k_prep(
    const void* g0,const void* b0,const void* m0,const void* v0,
    const void* g1,const void* b1,const void* m1,const void* v1,
    const void* g2,const void* b2,const void* m2,const void* v2,
    const void* g3,const void* b3,const void* m3,const void* v3,
    const int* __restrict__ flagp, float* scale, float* shift)
{
  const int t = threadIdx.x;
  if (t >= 512) return;
  const int flg = *flagp;
  const int set = t >> 7, c = t & 127;
  const void *gp,*bp,*mp,*vp;
  if      (set == 0){gp=g0;bp=b0;mp=m0;vp=v0;}
  else if (set == 1){gp=g1;bp=b1;mp=m1;vp=v1;}
  else if (set == 2){gp=g2;bp=b2;mp=m2;vp=v2;}
  else              {gp=g3;bp=b3;mp=m3;vp=v3;}
  const float sc = ldf(gp,c,flg) * rsqrtf(ldf(vp,c,flg) + 1e-5f);
  scale[t] = sc;
  shift[t] = ldf(bp,c,flg) - ldf(mp,c,flg) * sc;
}

// ---------------------------------------------------------------------------
// Weight reorder+convert for 3x3 convs: [co][ci][rs] -> bf16 [co][rs][ci]
// ---------------------------------------------------------------------------
__global__ void k_reorder_cvt(const void* __restrict__ win, const int* __restrict__ flagp,
                              u16* __restrict__ wout, int cin)
{
  const int idx = blockIdx.x * 256 + threadIdx.x;
  const int flg = *flagp;
  const int n9 = cin * 9;
  const int co = idx / n9;
  const int rem = idx - co * n9;
  const int ci = rem / 9;
  const int rs = rem - ci * 9;
  const u16 v = flg ? ((const u16*)win)[idx] : f2b(((const float*)win)[idx]);
  wout[co * n9 + rs * cin + ci] = v;
}

// ---------------------------------------------------------------------------
// Zero the 1-pixel halo of a padded pixel-major tensor [4][4356][C_]
// ---------------------------------------------------------------------------
template<int C_>
__global__ void k_halo(u16* __restrict__ buf)
{
  const int tid = blockIdx.x * 256 + threadIdx.x;
  const int e  = tid * 8;
  const int cc = e % C_;
  int rem = e / C_;
  const int hp = rem % 260;
  const int b  = rem / 260;
  int pix;
  if      (hp < 66)  pix = hp;
  else if (hp < 132) pix = 65 * 66 + (hp - 66);
  else if (hp < 196) pix = (hp - 132 + 1) * 66;
  else               pix = (hp - 196 + 1) * 66 + 65;
  uint4 z; z.x = 0; z.y = 0; z.z = 0; z.w = 0;
  *(uint4*)(buf + ((size_t)b * PPIX + pix) * C_ + cc) = z;
}

// ---------------------------------------------------------------------------
// x transpose: [b][512][4096] (fp32 or bf16) -> padded bf16 [b][4356][512]
// ---------------------------------------------------------------------------
__global__ __launch_bounds__(256) void k_xT(
    const void* __restrict__ src, const int* __restrict__ flagp, u16* __restrict__ dst)
{
  const int t = threadIdx.x, wave = t >> 6, lane = t & 63;
  const int pb = blockIdx.x & 31, ct = (blockIdx.x >> 5) & 7, b = blockIdx.x >> 8;
  const int c  = ct * 64 + lane;
  const int p0 = pb * 128 + wave * 32;
  const size_t sbase = ((size_t)(b * 512) + c) * 4096 + p0;

  u16 vals[32];
  if (*flagp){
    const u16* s = (const u16*)src + sbase;
    #pragma unroll
    for (int k = 0; k < 4; ++k){
      uint4 v = *(const uint4*)(s + k * 8);
      __builtin_memcpy(&vals[k * 8], &v, 16);
    }
  } else {
    const float* s = (const float*)src + sbase;
    #pragma unroll
    for (int k = 0; k < 8; ++k){
      float4 v = *(const float4*)(s + k * 4);
      vals[k*4+0] = f2b(v.x); vals[k*4+1] = f2b(v.y);
      vals[k*4+2] = f2b(v.z); vals[k*4+3] = f2b(v.w);
    }
  }
  const int hrow = (p0 >> 6) * 66 + (p0 & 63) + 67;
  u16* d = dst + ((size_t)b * PPIX + hrow) * 512 + c;
  #pragma unroll
  for (int k = 0; k < 32; ++k) d[(size_t)k * 512] = vals[k];
}

// ---------------------------------------------------------------------------
// Fused sibling 3x3 convs as LDS-tiled implicit GEMM (m97 structure).
// Grid 256 = cid(2 convs) x b(4) x 32 px-tiles of 128. Block 256 = 4 waves.
// Tile: 128 co x 128 px; wave (wc= w>>1, wp= w&1) owns 64co x 64px = 4x4 frags.
// K-loop: 9 taps x (CIN_/64) chunks; A (weights [co][rs*CIN+ci]) and
// B (x pixel-major [pix][CIN]) chunks staged via global_load_lds (16B/lane),
// columns XOR-swizzled by (row&7) to spread LDS banks.
// Epilogue: BN+ReLU, pixel-major store; conv B optionally dual-stores
// channel-major (outB2, for CAM).
// ---------------------------------------------------------------------------
template<int CIN_, bool PADOUT_, bool DUALB_>
__global__ __launch_bounds__(256, 1) void k_cgemm(
    const u16* __restrict__ xA, const u16* __restrict__ xB,
    const u16* __restrict__ wA, const u16* __restrict__ wB,
    const float* __restrict__ scale, const float* __restrict__ shift,
    u16* __restrict__ outA, u16* __restrict__ outBp, u16* __restrict__ outB2)
{
  constexpr int K9   = 9 * CIN_;
  constexpr int NCH  = CIN_ / 64;
  constexpr int OPIX = PADOUT_ ? PPIX : 4096;

  __shared__ __align__(16) u16 At[128 * 64];
  __shared__ __align__(16) u16 Bt[128 * 64];

  const int t = threadIdx.x;
  const int w = t >> 6, lane = t & 63;
  const int l16 = lane & 15, quad = lane >> 4;

  const int cid = blockIdx.x >> 7;
  const int t7  = blockIdx.x & 127;
  const int b   = t7 >> 5;
  const int p0  = (t7 & 31) << 7;

  const u16* xin = cid ? xB : xA;
  const u16* wK  = cid ? wB : wA;
  const float* sc = scale + cid * 128;
  const float* sh = shift + cid * 128;

  // staging: thread-fixed row/chunk; 4 rounds x 256 thr x 16B = 16KB per tile
  const int rowS = t >> 3;              // 0..31 (row within round)
  const int sw   = ((t & 7) ^ (rowS & 7)) << 3;  // swizzled column (elements)

  const u16* gA[4]; const u16* gB[4];
  u16* lA[4]; u16* lB[4];
  #pragma unroll
  for (int k = 0; k < 4; ++k){
    const int rA = k * 32 + rowS;
    gA[k] = wK + (size_t)rA * K9 + sw;
    const int px = p0 + k * 32 + rowS;
    const int h = px >> 6, wc = px & 63;
    gB[k] = xin + ((size_t)b * PPIX + h * 66 + wc) * CIN_ + sw;
    lA[k] = At + k * 2048 + w * 512;    // wave-uniform LDS bases
    lB[k] = Bt + k * 2048 + w * 512;
  }

  f32x4 acc[4][4];
  #pragma unroll
  for (int mi = 0; mi < 4; ++mi)
    #pragma unroll
    for (int ni = 0; ni < 4; ++ni){
      acc[mi][ni][0]=0.f; acc[mi][ni][1]=0.f; acc[mi][ni][2]=0.f; acc[mi][ni][3]=0.f;
    }

  const int wc4 = (w >> 1) << 6;   // wave co base
  const int wp4 = (w & 1) << 6;    // wave px base

  #pragma unroll 1
  for (int tap = 0; tap < 9; ++tap){
    const int tb = (tap / 3) * 66 + (tap % 3);   // pixel offset of tap
    #pragma unroll 1
    for (int cc = 0; cc < NCH; ++cc){
      const int offA = tap * CIN_ + cc * 64;
      const int offB = tb  * CIN_ + cc * 64;
      #pragma unroll
      for (int k = 0; k < 4; ++k){
        gload_lds16(gA[k] + offA, lA[k]);
        gload_lds16(gB[k] + offB, lB[k]);
      }
      __syncthreads();   // compiler drains vmcnt before barrier -> tiles ready
      #pragma unroll
      for (int ks = 0; ks < 2; ++ks){
        bf16x8 af[4], bf[4];
        const int col = ((ks * 4 + quad) ^ (l16 & 7)) << 3;
        #pragma unroll
        for (int mi = 0; mi < 4; ++mi)
          af[mi] = *(const bf16x8*)(At + ((wc4 + mi * 16 + l16) << 6) + col);
        #pragma unroll
        for (int ni = 0; ni < 4; ++ni)
          bf[ni] = *(const bf16x8*)(Bt + ((wp4 + ni * 16 + l16) << 6) + col);
        #pragma unroll
        for (int mi = 0; mi < 4; ++mi)
          #pragma unroll
          for (int ni = 0; ni < 4; ++ni)
            acc[mi][ni] = __builtin_amdgcn_mfma_f32_16x16x32_bf16(af[mi], bf[ni], acc[mi][ni], 0, 0, 0);
      }
      __syncthreads();   // all ds_reads done before next chunk overwrites
    }
  }

  u16* outp = cid ? outBp : outA;
  #pragma unroll
  for (int mi = 0; mi < 4; ++mi){
    #pragma unroll
    for (int ni = 0; ni < 4; ++ni){
      const int px = p0 + wp4 + ni * 16 + l16;
      const int opix = PADOUT_ ? ((px >> 6) * 66 + (px & 63) + 67) : px;
      const int co4 = wc4 + mi * 16 + quad * 4;
      u16 pk[4];
      #pragma unroll
      for (int rr = 0; rr < 4; ++rr)
        pk[rr] = f2b(fmaxf(acc[mi][ni][rr] * sc[co4 + rr] + sh[co4 + rr], 0.f));
      u64 pkv; __builtin_memcpy(&pkv, pk, 8);
      *(u64*)(outp + ((size_t)b * OPIX + opix) * 128 + co4) = pkv;
      if constexpr (DUALB_){
        if (cid){
          #pragma unroll
          for (int rr = 0; rr < 4; ++rr)
            outB2[((size_t)(b * 128) + co4 + rr) * 4096 + px] = pk[rr];
        }
      }
    }
  }
}

// ---------------------------------------------------------------------------
// 1x1 conv (MFMA), one wave per 16(co) x 16(px) tile; pixel-major input.
// EPI: 2 = +bias -> channel-major bf16
//      3 = +bias -> flag ? bf16 : fp32, channel-major (d_out heads)
//      4 = +bias -> qT hi/lo bf16 pair [b][4096][16]
// ---------------------------------------------------------------------------
template<int CIN_, int KH_, int CO_, int EPI_, bool SUM2_, bool PADIN_, bool PADOUT_>
__global__ __launch_bounds__(256) void k_convT(
    const u16* __restrict__ xin, const u16* __restrict__ xin2,
    const u16* __restrict__ wK,
    const float* __restrict__ scale, const float* __restrict__ shift,
    const void* __restrict__ bias, const int* __restrict__ flagp,
    u16* __restrict__ outB, float* __restrict__ outF, u16* __restrict__ outB2)
{
  constexpr int K    = CIN_ * KH_ * KH_;
  constexpr int MT   = CO_ / 16;
  constexpr int IPIX = PADIN_ ? PPIX : 4096;

  const int tid  = threadIdx.x;
  const int wave = tid >> 6;
  const int lane = tid & 63;
  const int l16  = lane & 15;
  const int quad = lane >> 4;

  int tile = blockIdx.x * 4 + wave;
  const int nt = tile & 255; tile >>= 8;
  const int mt = tile % MT;
  const int b  = tile / MT;

  const int p = nt * 16 + l16;
  const int h = p >> 6, wc = p & 63;

  const u16* wrow = wK + (size_t)(mt * 16 + l16) * K + quad * 8;
  const u16* xb   = xin + (size_t)b * IPIX * CIN_ + quad * 8;

  f32x4 acc = {0.f, 0.f, 0.f, 0.f};

  const int poff = PADIN_ ? (h * 66 + wc + 67) : p;
  const u16* xrs = xb + (size_t)poff * CIN_;
  const u16* xrs2 = nullptr;
  if constexpr (SUM2_) xrs2 = xin2 + (size_t)b * IPIX * CIN_ + quad * 8 + (size_t)poff * CIN_;
  #pragma unroll
  for (int ci0 = 0; ci0 < CIN_; ci0 += 32){
    bf16x8 af = *(const bf16x8*)(wrow + ci0);
    bf16x8 bf;
    if constexpr (SUM2_){
      bf16x8 b1 = *(const bf16x8*)(xrs + ci0);
      bf16x8 b2 = *(const bf16x8*)(xrs2 + ci0);
      #pragma unroll
      for (int j = 0; j < 8; ++j)
        bf[j] = (short)f2b(b2f((u16)b1[j]) + b2f((u16)b2[j]));
    } else {
      bf = *(const bf16x8*)(xrs + ci0);
    }
    acc = __builtin_amdgcn_mfma_f32_16x16x32_bf16(af, bf, acc, 0, 0, 0);
  }

  const int flg = *flagp;

  if constexpr (EPI_ == 4){
    #pragma unroll
    for (int rr = 0; rr < 4; ++rr){
      const int co = quad * 4 + rr;   // MT == 1
      const float vv = acc[rr] + ldf(bias, co, flg);
      const u16 hb = f2b(vv);
      const float lo = vv - b2f(hb);
      const size_t qaddr = ((size_t)b * 4096 + p) * 16 + co;
      outB[qaddr] = hb;
      ((u16*)outF)[qaddr] = f2b(lo);
    }
  } else {
    #pragma unroll
    for (int rr = 0; rr < 4; ++rr){
      const int co = mt * 16 + quad * 4 + rr;
      const float vv = acc[rr] + ldf(bias, co, flg);
      const size_t addr = ((size_t)(b * CO_) + co) * 4096 + p;
      if constexpr (EPI_ == 2) outB[addr] = f2b(vv);
      else { if (flg) outB[addr] = f2b(vv); else outF[addr] = vv; }
    }
  }
  (void)outB2;
}

// ---------------------------------------------------------------------------
// PAM flash attention: grid 1024 = b x 64 i-tile x 4 j-seg.
// ---------------------------------------------------------------------------
__global__ __launch_bounds__(256) void k_pam_flash(
    const u16* __restrict__ qTh, const u16* __restrict__ qTl,
    const u16* __restrict__ v,
    u16* __restrict__ po, float* __restrict__ pm, float* __restrict__ pl)
{
  __shared__ u16 vls[128 * 72];
  __shared__ u16 pls[64 * 72];

  const int t    = threadIdx.x;
  const int wave = t >> 6, lane = t & 63;
  const int l16  = lane & 15, quad = lane >> 4;

  const int bid = blockIdx.x;
  const int js  = bid & 3, it = (bid >> 2) & 63, b = bid >> 8;
  const int i0  = it * 64;
  const int jbase = js * 1024;

  const u16* qTbh = qTh + ((size_t)b * 4096) * 16;
  const u16* qTbl = qTl + ((size_t)b * 4096) * 16;
  const u16* vb   = v + ((size_t)b * 128) * 4096;

  bf16x8 afh = {}, afl = {};
  {
    const int i = i0 + wave * 16 + l16;
    if (quad < 2){
      *(uint4*)&afh = *(const uint4*)(qTbh + (size_t)i * 16 + quad * 8);
      *(uint4*)&afl = *(const uint4*)(qTbl + (size_t)i * 16 + quad * 8);
    }
  }

  f32x4 oacc[8];
  #pragma unroll
  for (int cs = 0; cs < 8; ++cs){ oacc[cs][0]=0.f; oacc[cs][1]=0.f; oacc[cs][2]=0.f; oacc[cs][3]=0.f; }
  float m_run[4], l_run[4];
  #pragma unroll
  for (int r = 0; r < 4; ++r){ m_run[r] = -1e30f; l_run[r] = 0.f; }

  const int vc = t >> 1, vjh = (t & 1) * 32;

  for (int ch = 0; ch < 16; ++ch){
    const int j0 = jbase + ch * 64;
    __syncthreads();
    {
      const u16* src = vb + (size_t)vc * 4096 + j0 + vjh;
      u16* dst = vls + vc * 72 + vjh;
      *(uint4*)(dst)      = *(const uint4*)(src);
      *(uint4*)(dst + 8)  = *(const uint4*)(src + 8);
      *(uint4*)(dst + 16) = *(const uint4*)(src + 16);
      *(uint4*)(dst + 24) = *(const uint4*)(src + 24);
    }
    f32x4 sacc[4];
    #pragma unroll
    for (int ns = 0; ns < 4; ++ns){
      bf16x8 bh = {}, bl = {};
      const int j = j0 + ns * 16 + l16;
      if (quad < 2){
        *(uint4*)&bh = *(const uint4*)(qTbh + (size_t)j * 16 + quad * 8);
        *(uint4*)&bl = *(const uint4*)(qTbl + (size_t)j * 16 + quad * 8);
      }
      f32x4 z = {0.f, 0.f, 0.f, 0.f};
      z = __builtin_amdgcn_mfma_f32_16x16x32_bf16(afh, bh, z, 0, 0, 0);
      z = __builtin_amdgcn_mfma_f32_16x16x32_bf16(afh, bl, z, 0, 0, 0);
      z = __builtin_amdgcn_mfma_f32_16x16x32_bf16(afl, bh, z, 0, 0, 0);
      sacc[ns] = z;
    }
    float pv[4][4];
    #pragma unroll
    for (int r = 0; r < 4; ++r){
      float mx = fmaxf(fmaxf(sacc[0][r], sacc[1][r]), fmaxf(sacc[2][r], sacc[3][r]));
      mx = fmaxf(mx, __shfl_xor(mx, 1));
      mx = fmaxf(mx, __shfl_xor(mx, 2));
      mx = fmaxf(mx, __shfl_xor(mx, 4));
      mx = fmaxf(mx, __shfl_xor(mx, 8));
      const float mnew  = fmaxf(m_run[r], mx);
      const float alpha = __expf(m_run[r] - mnew);
      m_run[r] = mnew;
      float rs = 0.f;
      #pragma unroll
      for (int ns = 0; ns < 4; ++ns){
        pv[ns][r] = __expf(sacc[ns][r] - mnew);
        rs += pv[ns][r];
      }
      rs += __shfl_xor(rs, 1); rs += __shfl_xor(rs, 2);
      rs += __shfl_xor(rs, 4); rs += __shfl_xor(rs, 8);
      l_run[r] = l_run[r] * alpha + rs;
      #pragma unroll
      for (int cs = 0; cs < 8; ++cs) oacc[cs][r] *= alpha;
    }
    #pragma unroll
    for (int r = 0; r < 4; ++r)
      #pragma unroll
      for (int ns = 0; ns < 4; ++ns)
        pls[(wave * 16 + quad * 4 + r) * 72 + ns * 16 + l16] = f2b(pv[ns][r]);
    __syncthreads();
    #pragma unroll
    for (int ks = 0; ks < 2; ++ks){
      bf16x8 pf = *(const bf16x8*)(pls + (wave * 16 + l16) * 72 + ks * 32 + quad * 8);
      #pragma unroll
      for (int cs = 0; cs < 8; ++cs){
        bf16x8 vf = *(const bf16x8*)(vls + (cs * 16 + l16) * 72 + ks * 32 + quad * 8);
        oacc[cs] = __builtin_amdgcn_mfma_f32_16x16x32_bf16(pf, vf, oacc[cs], 0, 0, 0);
      }
    }
  }

  u16* pob = po + (size_t)bid * 64 * 128;
  #pragma unroll
  for (int cs = 0; cs < 8; ++cs)
    #pragma unroll
    for (int r = 0; r < 4; ++r)
      pob[(wave * 16 + quad * 4 + r) * 128 + cs * 16 + l16] = f2b(oacc[cs][r]);
  if (l16 == 0){
    #pragma unroll
    for (int r = 0; r < 4; ++r){
      pm[(size_t)bid * 64 + wave * 16 + quad * 4 + r] = m_run[r];
      pl[(size_t)bid * 64 + wave * 16 + quad * 4 + r] = l_run[r];
    }
  }
}

// ---------------------------------------------------------------------------
// PAM combine (pixel-major): merge 4 j-seg partials, gamma + residual,
// in-place over padded feat1_T. Grid 256 = b(4) x i-tile(64).
// ---------------------------------------------------------------------------
__global__ __launch_bounds__(256) void k_pam_comb2(
    const u16* __restrict__ po, const float* __restrict__ pm, const float* __restrict__ pl,
    const void* __restrict__ gptr, const int* __restrict__ flagp,
    u16* __restrict__ featT)
{
  __shared__ float wgt[4][64];
  const int t  = threadIdx.x;
  const int it = blockIdx.x & 63, b = blockIdx.x >> 6;
  const int base = (b * 64 + it) * 4;
  if (t < 64){
    const float m0 = pm[(size_t)(base+0)*64 + t];
    const float m1 = pm[(size_t)(base+1)*64 + t];
    const float m2 = pm[(size_t)(base+2)*64 + t];
    const float m3 = pm[(size_t)(base+3)*64 + t];
    const float M  = fmaxf(fmaxf(m0, m1), fmaxf(m2, m3));
    const float e0 = __expf(m0 - M), e1 = __expf(m1 - M);
    const float e2 = __expf(m2 - M), e3 = __expf(m3 - M);
    const float L  = pl[(size_t)(base+0)*64+t]*e0 + pl[(size_t)(base+1)*64+t]*e1
                   + pl[(size_t)(base+2)*64+t]*e2 + pl[(size_t)(base+3)*64+t]*e3;
    const float li = 1.0f / L;
    wgt[0][t] = e0*li; wgt[1][t] = e1*li; wgt[2][t] = e2*li; wgt[3][t] = e3*li;
  }
  __syncthreads();
  const float g = ldf(gptr, 0, *flagp);
  const int c = t & 127, ih = t >> 7;
  const int i0 = it * 64;
  for (int st = 0; st < 32; ++st){
    const int il = ih + st * 2;
    float acc = 0.f;
    #pragma unroll
    for (int s = 0; s < 4; ++s)
      acc += wgt[s][il] * b2f(po[((size_t)(base+s)*64 + il)*128 + c]);
    const int i = i0 + il;
    const int pix = (i >> 6) * 66 + (i & 63) + 67;
    u16* addr = featT + ((size_t)b * PPIX + pix) * 128 + c;
    *addr = f2b(g * acc + b2f(*addr));
  }
}

// ---------------------------------------------------------------------------
// CAM attention (channel-major feat2): writes attn^T bf16 [b][d][c].
// ---------------------------------------------------------------------------
__global__ __launch_bounds__(128) void k_cam_attn(
    const u16* __restrict__ f, u16* __restrict__ attnT)
{
  __shared__ float fc[4096];
  __shared__ float red[128];
  const int d = threadIdx.x;
  const int c = blockIdx.x & 127, b = blockIdx.x >> 7;
  const u16* fb   = f + (size_t)b * 128 * HW;
  const u16* rowc = fb + (size_t)c * HW;
  for (int mi = d; mi < 4096; mi += 128) fc[mi] = b2f(rowc[mi]);
  __syncthreads();

  const u16* rowd = fb + (size_t)d * HW;
  float e = 0.f;
  for (int mm = 0; mm < 4096; mm += 8){
    const uint4 xv = *(const uint4*)(rowd + mm);
    const u16* px = (const u16*)&xv;
    #pragma unroll
    for (int k = 0; k < 8; ++k) e += fc[mm + k] * b2f(px[k]);
  }
  red[d] = e;
  __syncthreads();
  for (int st = 64; st > 0; st >>= 1){
    if (d < st) red[d] = fminf(red[d], red[d + st]);
    __syncthreads();
  }
  const float emin = red[0];
  __syncthreads();
  const float pd = __expf(emin - e);
  red[d] = pd;
  __syncthreads();
  for (int st = 64; st > 0; st >>= 1){
    if (d < st) red[d] += red[d + st];
    __syncthreads();
  }
  attnT[((size_t)b * 128 + d) * 128 + c] = f2b(pd / red[0]);
}

// ---------------------------------------------------------------------------
// CAM output: cafeat_T[m][c] = gamma * sum_d attnT[d][c] f_cm[d][m] + f_T[m][c]
// ---------------------------------------------------------------------------
__global__ __launch_bounds__(256) void k_cam_out2(
    const u16* __restrict__ fcm, const u16* __restrict__ fT,
    const u16* __restrict__ attnT, const void* __restrict__ gptr,
    const int* __restrict__ flagp, u16* __restrict__ outT)
{
  __shared__ u16 als[128 * 128];
  const int t = threadIdx.x;
  const int b = blockIdx.x >> 8, m0 = (blockIdx.x & 255) * 16;
  {
    const uint4* src = (const uint4*)(attnT + (size_t)b * 128 * 128);
    uint4* dstl = (uint4*)als;
    #pragma unroll
    for (int k = 0; k < 8; ++k) dstl[t + k * 256] = src[t + k * 256];
  }
  __syncthreads();
  const int c = t & 127, mg = t >> 7;
  const int m = m0 + mg * 8;
  const u16* frow = fcm + (size_t)b * 128 * HW + m;
  float acc[8];
  #pragma unroll
  for (int k = 0; k < 8; ++k) acc[k] = 0.f;
  for (int d = 0; d < 128; ++d){
    const float ad = b2f(als[d * 128 + c]);
    const uint4 fv = *(const uint4*)(frow + (size_t)d * HW);
    const u16* pf = (const u16*)&fv;
    #pragma unroll
    for (int k = 0; k < 8; ++k) acc[k] += ad * b2f(pf[k]);
  }
  const float g = ldf(gptr, 0, *flagp);
  const int hrow = (m >> 6) * 66 + (m & 63) + 67;
  #pragma unroll
  for (int k = 0; k < 8; ++k){
    const size_t addr = ((size_t)b * PPIX + hrow + k) * 128 + c;
    outT[addr] = f2b(g * acc[k] + b2f(fT[addr]));
  }
}

// ---------------------------------------------------------------------------
extern "C" void kernel_launch(void* const* d_in, const int* in_sizes, int n_in,
                              void* d_out, int out_size, void* d_ws, size_t ws_size,
                              hipStream_t stream)
{
  (void)in_sizes; (void)n_in; (void)out_size; (void)ws_size;

  const void* x    = d_in[0];
  const void* w11  = d_in[1];
  const void* g11  = d_in[2];
  const void* b11  = d_in[3];
  const void* m11  = d_in[4];
  const void* v11  = d_in[5];
  const void* w12  = d_in[6];
  const void* g12  = d_in[7];
  const void* b12  = d_in[8];
  const void* m12  = d_in[9];
  const void* v12  = d_in[10];
  const void* kw   = d_in[11];
  const void* kb   = d_in[12];
  const void* vw   = d_in[13];
  const void* vb   = d_in[14];
  const void* pgam = d_in[15];
  const void* cgam = d_in[16];
  const void* w21  = d_in[17];
  const void* g21  = d_in[18];
  const void* b21  = d_in[19];
  const void* m21  = d_in[20];
  const void* v21  = d_in[21];
  const void* w22  = d_in[22];
  const void* g22  = d_in[23];
  const void* b22  = d_in[24];
  const void* m22  = d_in[25];
  const void* v22  = d_in[26];
  const void* w31  = d_in[27];
  const void* b31  = d_in[28];
  const void* w32  = d_in[29];
  const void* b32  = d_in[30];
  const void* w4   = d_in[31];
  const void* b4   = d_in[32];

  char* wsb = (char*)d_ws;
  size_t off = 0;
  auto alloc = [&](size_t bytes) -> void* {
    void* pp = wsb + off;
    off += (bytes + 255) & ~(size_t)255;
    return pp;
  };
  u16*   xT      = (u16*)alloc((size_t)4 * PPIX * 512 * 2);  // dead after trunk -> po
  u16*   feat1T  = (u16*)alloc((size_t)4 * PPIX * 128 * 2);  // padded; later pa_feat (in-place)
  u16*   feat2T  = (u16*)alloc((size_t)4 * PPIX * 128 * 2);  // padded (residual reads)
  u16*   feat2cm = (u16*)alloc((size_t)4 * 128 * HW * 2);    // channel-major (CAM)
  u16*   cafeatT = (u16*)alloc((size_t)4 * PPIX * 128 * 2);  // padded
  u16*   vbuf    = (u16*)alloc((size_t)4 * 128 * HW * 2);    // v cm; later pa_conv_T (unpadded)
  u16*   caconvT = (u16*)alloc((size_t)4 * HW * 128 * 2);    // unpadded pixel-major
  u16*   qTh     = (u16*)alloc((size_t)4 * HW * 16 * 2);
  u16*   qTl     = (u16*)alloc((size_t)4 * HW * 16 * 2);
  float* pm      = (float*)alloc((size_t)1024 * 64 * 4);
  float* pl      = (float*)alloc((size_t)1024 * 64 * 4);
  u16*   attnT   = (u16*)alloc((size_t)4 * 128 * 128 * 2);
  float* scale   = (float*)alloc(512 * 4);
  float* shift   = (float*)alloc(512 * 4);
  u16*   w11r    = (u16*)alloc((size_t)128 * 4608 * 2);
  u16*   w12r    = (u16*)alloc((size_t)128 * 4608 * 2);
  u16*   w21r    = (u16*)alloc((size_t)128 * 1152 * 2);
  u16*   w22r    = (u16*)alloc((size_t)128 * 1152 * 2);
  u16*   kwb     = (u16*)alloc((size_t)16 * 128 * 2);
  u16*   vwb     = (u16*)alloc((size_t)128 * 128 * 2);
  u16*   w31b    = (u16*)alloc((size_t)64 * 128 * 2);
  u16*   w32b    = (u16*)alloc((size_t)64 * 128 * 2);
  u16*   w4b     = (u16*)alloc((size_t)64 * 128 * 2);
  int*   flag    = (int*)alloc(256);
  u16*   po      = xT;   // 16.8 MB <= xT's 17.8 MB; xT dead after trunk convs

  // prep
  k_detect<<<1, 512, 0, stream>>>((const u32*)x, flag);
  k_prep<<<1, 512, 0, stream>>>(g11,b11,m11,v11, g12,b12,m12,v12,
                                g21,b21,m21,v21, g22,b22,m22,v22, flag, scale, shift);
  k_halo<512><<<260, 256, 0, stream>>>(xT);
  k_halo<128><<<65, 256, 0, stream>>>(feat1T);
  k_halo<128><<<65, 256, 0, stream>>>(cafeatT);
  k_xT<<<1024, 256, 0, stream>>>(x, flag, xT);
  k_reorder_cvt<<<2304, 256, 0, stream>>>(w11, flag, w11r, 512);
  k_reorder_cvt<<<2304, 256, 0, stream>>>(w12, flag, w12r, 512);
  k_reorder_cvt<<<576, 256, 0, stream>>>(w21, flag, w21r, 128);
  k_reorder_cvt<<<576, 256, 0, stream>>>(w22, flag, w22r, 128);
  k_cvt<<<2, 256, 0, stream>>>(kw, flag, kwb, 16 * 128);
  k_cvt<<<16, 256, 0, stream>>>(vw, flag, vwb, 128 * 128);
  k_cvt<<<8, 256, 0, stream>>>(w31, flag, w31b, 64 * 128);
  k_cvt<<<8, 256, 0, stream>>>(w32, flag, w32b, 64 * 128);
  k_cvt<<<8, 256, 0, stream>>>(w4, flag, w4b, 64 * 128);

  // trunk convs, fused LDS-GEMM (one dispatch, 256 blocks)
  k_cgemm<512, true, true><<<256, 256, 0, stream>>>(
      xT, xT, w11r, w12r, scale, shift, feat1T, feat2T, feat2cm);

  // PAM
  k_convT<128,1,16,4,false,true,false><<<256,256,0,stream>>>(
      feat1T, nullptr, kwb, nullptr, nullptr, kb, flag, qTh, (float*)qTl, nullptr);
  k_convT<128,1,128,2,false,true,false><<<2048,256,0,stream>>>(
      feat1T, nullptr, vwb, nullptr, nullptr, vb, flag, vbuf, nullptr, nullptr);
  k_pam_flash<<<1024, 256, 0, stream>>>(qTh, qTl, vbuf, po, pm, pl);
  k_pam_comb2<<<256, 256, 0, stream>>>(po, pm, pl, pgam, flag, feat1T);  // -> pa_feat

  // CAM
  k_cam_attn<<<512, 128, 0, stream>>>(feat2cm, attnT);
  k_cam_out2<<<1024, 256, 0, stream>>>(feat2cm, feat2T, attnT, cgam, flag, cafeatT);

  // second convs, fused LDS-GEMM (unpadded pixel-major outputs)
  k_cgemm<128, false, false><<<256, 256, 0, stream>>>(
      feat1T, cafeatT, w21r, w22r, scale + 256, shift + 256, vbuf, caconvT, nullptr);

  // heads -> d_out [3][4][64][4096], channel-major, dtype per flag
  const size_t SEC = (size_t)4 * 64 * HW;
  u16*   outB = (u16*)d_out;
  float* outF = (float*)d_out;
  k_convT<128,1,64,3,false,false,false><<<1024,256,0,stream>>>(
      vbuf,    nullptr, w31b, nullptr, nullptr, b31, flag, outB,           outF,           nullptr);
  k_convT<128,1,64,3,false,false,false><<<1024,256,0,stream>>>(
      caconvT, nullptr, w32b, nullptr, nullptr, b32, flag, outB + SEC,     outF + SEC,     nullptr);
  k_convT<128,1,64,3,true ,false,false><<<1024,256,0,stream>>>(
      vbuf,    caconvT, w4b,  nullptr, nullptr, b4,  flag, outB + 2 * SEC, outF + 2 * SEC, nullptr);
}

// Round 6
// 480.184 us; speedup vs baseline: 2.1490x; 1.0354x over previous
//
#include <hip/hip_runtime.h>
#include <stdint.h>

typedef unsigned short u16;
typedef unsigned int   u32;
typedef unsigned long long u64;
typedef __attribute__((ext_vector_type(8))) short bf16x8;
typedef __attribute__((ext_vector_type(4))) float f32x4;

#define DEV static __device__ __forceinline__

DEV float b2f(u16 u){ u32 x = ((u32)u) << 16; float f; __builtin_memcpy(&f, &x, 4); return f; }
DEV u16 f2b(float f){ u32 x; __builtin_memcpy(&x, &f, 4); return (u16)((x + 0x7fffu + ((x >> 16) & 1u)) >> 16); }
DEV float ldf(const void* p, int i, int flg){
  return flg ? b2f(((const u16*)p)[i]) : ((const float*)p)[i];
}
// async global->LDS, 16B per lane; LDS dest = wave-uniform base + lane*16
DEV void gload_lds16(const u16* g, u16* l){
  __builtin_amdgcn_global_load_lds((const __attribute__((address_space(1))) void*)g,
                                   (__attribute__((address_space(3))) void*)l, 16, 0, 0);
}

// Dims: B=4, H=W=64, HW=4096, Cin=512, Cm=128, Ck=16, Cout=64
// Padded pixel space: 66x66 = 4356, interior pixel (h,w) -> h*66+w+67
static constexpr int HW   = 4096;
static constexpr int PPIX = 4356;

// ---------------------------------------------------------------------------
__global__ void k_detect(const u32* __restrict__ x, int* __restrict__ flag)
{
  __shared__ int cnt;
  if (threadIdx.x == 0) cnt = 0;
  __syncthreads();
  const u32 w  = x[threadIdx.x];
  const u32 eb = (w >> 7) & 0xFFu;
  if (eb >= 100u && eb <= 150u) atomicAdd(&cnt, 1);
  __syncthreads();
  if (threadIdx.x == 0) *flag = (cnt > 384) ? 1 : 0;
}

// ---------------------------------------------------------------------------
__global__ void k_cvt(const void* __restrict__ src, const int* __restrict__ flagp,
                      u16* __restrict__ dst, int n)
{
  const int i = (blockIdx.x * 256 + threadIdx.x) << 2;
  if (i >= n) return;
  u64 ov;
  if (*flagp){
    ov = ((const u64*)src)[i >> 2];
  } else {
    const float4 f = ((const float4*)src)[i >> 2];
    const u16 a0 = f2b(f.x), a1 = f2b(f.y), a2 = f2b(f.z), a3 = f2b(f.w);
    ov = (u64)a0 | ((u64)a1 << 16) | ((u64)a2 << 32) | ((u64)a3 << 48);
  }
  ((u64*)dst)[i >> 2] = ov;
}

// ---------------------------------------------------------------------------
__global__ void k_prep(
    const void* g0,const void* b0,const void* m0,const void* v0,
    const void* g1,const void* b1,const void* m1,const void* v1,
    const void* g2,const void* b2,const void* m2,const void* v2,
    const void* g3,const void* b3,const void* m3,const void* v3,
    const int* __restrict__ flagp, float* scale, float* shift)
{
  const int t = threadIdx.x;
  if (t >= 512) return;
  const int flg = *flagp;
  const int set = t >> 7, c = t & 127;
  const void *gp,*bp,*mp,*vp;
  if      (set == 0){gp=g0;bp=b0;mp=m0;vp=v0;}
  else if (set == 1){gp=g1;bp=b1;mp=m1;vp=v1;}
  else if (set == 2){gp=g2;bp=b2;mp=m2;vp=v2;}
  else              {gp=g3;bp=b3;mp=m3;vp=v3;}
  const float sc = ldf(gp,c,flg) * rsqrtf(ldf(vp,c,flg) + 1e-5f);
  scale[t] = sc;
  shift[t] = ldf(bp,c,flg) - ldf(mp,c,flg) * sc;
}

// ---------------------------------------------------------------------------
// Weight reorder+convert for 3x3 convs: [co][ci][rs] -> bf16 [co][rs][ci]
// ---------------------------------------------------------------------------
__global__ void k_reorder_cvt(const void* __restrict__ win, const int* __restrict__ flagp,
                              u16* __restrict__ wout, int cin)
{
  const int idx = blockIdx.x * 256 + threadIdx.x;
  const int flg = *flagp;
  const int n9 = cin * 9;
  const int co = idx / n9;
  const int rem = idx - co * n9;
  const int ci = rem / 9;
  const int rs = rem - ci * 9;
  const u16 v = flg ? ((const u16*)win)[idx] : f2b(((const float*)win)[idx]);
  wout[co * n9 + rs * cin + ci] = v;
}

// ---------------------------------------------------------------------------
// Zero the 1-pixel halo of a padded pixel-major tensor [4][4356][C_]
// ---------------------------------------------------------------------------
template<int C_>
__global__ void k_halo(u16* __restrict__ buf)
{
  const int tid = blockIdx.x * 256 + threadIdx.x;
  const int e  = tid * 8;
  const int cc = e % C_;
  int rem = e / C_;
  const int hp = rem % 260;
  const int b  = rem / 260;
  int pix;
  if      (hp < 66)  pix = hp;
  else if (hp < 132) pix = 65 * 66 + (hp - 66);
  else if (hp < 196) pix = (hp - 132 + 1) * 66;
  else               pix = (hp - 196 + 1) * 66 + 65;
  uint4 z; z.x = 0; z.y = 0; z.z = 0; z.w = 0;
  *(uint4*)(buf + ((size_t)b * PPIX + pix) * C_ + cc) = z;
}

// ---------------------------------------------------------------------------
// x transpose: [b][512][4096] (fp32 or bf16) -> padded bf16 [b][4356][512]
// ---------------------------------------------------------------------------
__global__ __launch_bounds__(256) void k_xT(
    const void* __restrict__ src, const int* __restrict__ flagp, u16* __restrict__ dst)
{
  const int t = threadIdx.x, wave = t >> 6, lane = t & 63;
  const int pb = blockIdx.x & 31, ct = (blockIdx.x >> 5) & 7, b = blockIdx.x >> 8;
  const int c  = ct * 64 + lane;
  const int p0 = pb * 128 + wave * 32;
  const size_t sbase = ((size_t)(b * 512) + c) * 4096 + p0;

  u16 vals[32];
  if (*flagp){
    const u16* s = (const u16*)src + sbase;
    #pragma unroll
    for (int k = 0; k < 4; ++k){
      uint4 v = *(const uint4*)(s + k * 8);
      __builtin_memcpy(&vals[k * 8], &v, 16);
    }
  } else {
    const float* s = (const float*)src + sbase;
    #pragma unroll
    for (int k = 0; k < 8; ++k){
      float4 v = *(const float4*)(s + k * 4);
      vals[k*4+0] = f2b(v.x); vals[k*4+1] = f2b(v.y);
      vals[k*4+2] = f2b(v.z); vals[k*4+3] = f2b(v.w);
    }
  }
  const int hrow = (p0 >> 6) * 66 + (p0 & 63) + 67;
  u16* d = dst + ((size_t)b * PPIX + hrow) * 512 + c;
  #pragma unroll
  for (int k = 0; k < 32; ++k) d[(size_t)k * 512] = vals[k];
}

// ---------------------------------------------------------------------------
// Fused sibling 3x3 convs as LDS-tiled implicit GEMM (m97 structure).
// ---------------------------------------------------------------------------
template<int CIN_, bool PADOUT_, bool DUALB_>
__global__ __launch_bounds__(256, 1) void k_cgemm(
    const u16* __restrict__ xA, const u16* __restrict__ xB,
    const u16* __restrict__ wA, const u16* __restrict__ wB,
    const float* __restrict__ scale, const float* __restrict__ shift,
    u16* __restrict__ outA, u16* __restrict__ outBp, u16* __restrict__ outB2)
{
  constexpr int K9   = 9 * CIN_;
  constexpr int NCH  = CIN_ / 64;
  constexpr int OPIX = PADOUT_ ? PPIX : 4096;

  __shared__ __align__(16) u16 At[128 * 64];
  __shared__ __align__(16) u16 Bt[128 * 64];

  const int t = threadIdx.x;
  const int w = t >> 6, lane = t & 63;
  const int l16 = lane & 15, quad = lane >> 4;

  const int cid = blockIdx.x >> 7;
  const int t7  = blockIdx.x & 127;
  const int b   = t7 >> 5;
  const int p0  = (t7 & 31) << 7;

  const u16* xin = cid ? xB : xA;
  const u16* wK  = cid ? wB : wA;
  const float* sc = scale + cid * 128;
  const float* sh = shift + cid * 128;

  const int rowS = t >> 3;
  const int sw   = ((t & 7) ^ (rowS & 7)) << 3;

  const u16* gA[4]; const u16* gB[4];
  u16* lA[4]; u16* lB[4];
  #pragma unroll
  for (int k = 0; k < 4; ++k){
    const int rA = k * 32 + rowS;
    gA[k] = wK + (size_t)rA * K9 + sw;
    const int px = p0 + k * 32 + rowS;
    const int h = px >> 6, wc = px & 63;
    gB[k] = xin + ((size_t)b * PPIX + h * 66 + wc) * CIN_ + sw;
    lA[k] = At + k * 2048 + w * 512;
    lB[k] = Bt + k * 2048 + w * 512;
  }

  f32x4 acc[4][4];
  #pragma unroll
  for (int mi = 0; mi < 4; ++mi)
    #pragma unroll
    for (int ni = 0; ni < 4; ++ni){
      acc[mi][ni][0]=0.f; acc[mi][ni][1]=0.f; acc[mi][ni][2]=0.f; acc[mi][ni][3]=0.f;
    }

  const int wc4 = (w >> 1) << 6;
  const int wp4 = (w & 1) << 6;

  #pragma unroll 1
  for (int tap = 0; tap < 9; ++tap){
    const int tb = (tap / 3) * 66 + (tap % 3);
    #pragma unroll 1
    for (int cc = 0; cc < NCH; ++cc){
      const int offA = tap * CIN_ + cc * 64;
      const int offB = tb  * CIN_ + cc * 64;
      #pragma unroll
      for (int k = 0; k < 4; ++k){
        gload_lds16(gA[k] + offA, lA[k]);
        gload_lds16(gB[k] + offB, lB[k]);
      }
      __syncthreads();
      #pragma unroll
      for (int ks = 0; ks < 2; ++ks){
        bf16x8 af[4], bf[4];
        const int col = ((ks * 4 + quad) ^ (l16 & 7)) << 3;
        #pragma unroll
        for (int mi = 0; mi < 4; ++mi)
          af[mi] = *(const bf16x8*)(At + ((wc4 + mi * 16 + l16) << 6) + col);
        #pragma unroll
        for (int ni = 0; ni < 4; ++ni)
          bf[ni] = *(const bf16x8*)(Bt + ((wp4 + ni * 16 + l16) << 6) + col);
        #pragma unroll
        for (int mi = 0; mi < 4; ++mi)
          #pragma unroll
          for (int ni = 0; ni < 4; ++ni)
            acc[mi][ni] = __builtin_amdgcn_mfma_f32_16x16x32_bf16(af[mi], bf[ni], acc[mi][ni], 0, 0, 0);
      }
      __syncthreads();
    }
  }

  u16* outp = cid ? outBp : outA;
  #pragma unroll
  for (int mi = 0; mi < 4; ++mi){
    #pragma unroll
    for (int ni = 0; ni < 4; ++ni){
      const int px = p0 + wp4 + ni * 16 + l16;
      const int opix = PADOUT_ ? ((px >> 6) * 66 + (px & 63) + 67) : px;
      const int co4 = wc4 + mi * 16 + quad * 4;
      u16 pk[4];
      #pragma unroll
      for (int rr = 0; rr < 4; ++rr)
        pk[rr] = f2b(fmaxf(acc[mi][ni][rr] * sc[co4 + rr] + sh[co4 + rr], 0.f));
      u64 pkv; __builtin_memcpy(&pkv, pk, 8);
      *(u64*)(outp + ((size_t)b * OPIX + opix) * 128 + co4) = pkv;
      if constexpr (DUALB_){
        if (cid){
          #pragma unroll
          for (int rr = 0; rr < 4; ++rr)
            outB2[((size_t)(b * 128) + co4 + rr) * 4096 + px] = pk[rr];
        }
      }
    }
  }
}

// ---------------------------------------------------------------------------
// 1x1 conv (MFMA), one wave per 16(co) x 16(px) tile; pixel-major input.
// EPI: 2 = +bias -> channel-major bf16
//      3 = +bias -> flag ? bf16 : fp32, channel-major (d_out heads)
//      4 = +bias -> qT hi/lo bf16 pair [b][4096][16]
//      6 = CAM: gamma*acc + residual(xin2, padded pixel-major) -> padded pm out
// WPB_: weights indexed per batch (wK + b*CO*K) — used for CAM attn GEMM.
// ---------------------------------------------------------------------------
template<int CIN_, int CO_, int EPI_, bool SUM2_, bool PADIN_, bool PADOUT_, bool WPB_>
__global__ __launch_bounds__(256) void k_convT(
    const u16* __restrict__ xin, const u16* __restrict__ xin2,
    const u16* __restrict__ wK,
    const void* __restrict__ bias, const int* __restrict__ flagp,
    u16* __restrict__ outB, float* __restrict__ outF)
{
  constexpr int K    = CIN_;
  constexpr int MT   = CO_ / 16;
  constexpr int IPIX = PADIN_ ? PPIX : 4096;
  constexpr int OPIX = PADOUT_ ? PPIX : 4096;

  const int tid  = threadIdx.x;
  const int wave = tid >> 6;
  const int lane = tid & 63;
  const int l16  = lane & 15;
  const int quad = lane >> 4;

  int tile = blockIdx.x * 4 + wave;
  const int nt = tile & 255; tile >>= 8;
  const int mt = tile % MT;
  const int b  = tile / MT;

  const int p = nt * 16 + l16;
  const int h = p >> 6, wc = p & 63;

  const u16* wrow = wK + (WPB_ ? (size_t)b * CO_ * K : 0)
                       + (size_t)(mt * 16 + l16) * K + quad * 8;
  const u16* xb   = xin + (size_t)b * IPIX * CIN_ + quad * 8;

  f32x4 acc = {0.f, 0.f, 0.f, 0.f};

  const int poff = PADIN_ ? (h * 66 + wc + 67) : p;
  const u16* xrs = xb + (size_t)poff * CIN_;
  const u16* xrs2 = nullptr;
  if constexpr (SUM2_) xrs2 = xin2 + (size_t)b * IPIX * CIN_ + quad * 8 + (size_t)poff * CIN_;
  #pragma unroll
  for (int ci0 = 0; ci0 < CIN_; ci0 += 32){
    bf16x8 af = *(const bf16x8*)(wrow + ci0);
    bf16x8 bf;
    if constexpr (SUM2_){
      bf16x8 b1 = *(const bf16x8*)(xrs + ci0);
      bf16x8 b2 = *(const bf16x8*)(xrs2 + ci0);
      #pragma unroll
      for (int j = 0; j < 8; ++j)
        bf[j] = (short)f2b(b2f((u16)b1[j]) + b2f((u16)b2[j]));
    } else {
      bf = *(const bf16x8*)(xrs + ci0);
    }
    acc = __builtin_amdgcn_mfma_f32_16x16x32_bf16(af, bf, acc, 0, 0, 0);
  }

  const int flg = *flagp;

  if constexpr (EPI_ == 4){
    #pragma unroll
    for (int rr = 0; rr < 4; ++rr){
      const int co = quad * 4 + rr;   // MT == 1
      const float vv = acc[rr] + ldf(bias, co, flg);
      const u16 hb = f2b(vv);
      const float lo = vv - b2f(hb);
      const size_t qaddr = ((size_t)b * 4096 + p) * 16 + co;
      outB[qaddr] = hb;
      ((u16*)outF)[qaddr] = f2b(lo);
    }
  } else if constexpr (EPI_ == 6){
    const float g = ldf(bias, 0, flg);
    const int opix = PADOUT_ ? (h * 66 + wc + 67) : p;
    const int co4 = mt * 16 + quad * 4;
    const size_t addr = ((size_t)b * OPIX + opix) * CO_ + co4;
    u64 rv = *(const u64*)(xin2 + (size_t)b * OPIX * CO_ + (size_t)opix * CO_ + co4);
    u16 rk[4]; __builtin_memcpy(rk, &rv, 8);
    u16 pk[4];
    #pragma unroll
    for (int rr = 0; rr < 4; ++rr)
      pk[rr] = f2b(g * acc[rr] + b2f(rk[rr]));
    u64 pkv; __builtin_memcpy(&pkv, pk, 8);
    *(u64*)(outB + addr) = pkv;
  } else {
    #pragma unroll
    for (int rr = 0; rr < 4; ++rr){
      const int co = mt * 16 + quad * 4 + rr;
      const float vv = acc[rr] + ldf(bias, co, flg);
      const size_t addr = ((size_t)(b * CO_) + co) * 4096 + p;
      if constexpr (EPI_ == 2) outB[addr] = f2b(vv);
      else { if (flg) outB[addr] = f2b(vv); else outF[addr] = vv; }
    }
  }
}

// ---------------------------------------------------------------------------
// PAM flash attention v2: F-layout LDS (conflict-free b128 frag reads),
// global_load_lds V staging, 2-MFMA hi/lo QK^T.
// Grid 1024 = b x 64 i-tile x 4 j-seg. Block 256 = 4 waves.
// ---------------------------------------------------------------------------
__global__ __launch_bounds__(256) void k_pam_flash(
    const u16* __restrict__ qTh, const u16* __restrict__ qTl,
    const u16* __restrict__ v,
    u16* __restrict__ po, float* __restrict__ pm, float* __restrict__ pl)
{
  // piece p = (cs*2+ks)*64 + lane, 8 u16 each: reads are base + lane*16B
  __shared__ __align__(16) u16 vls[1024 * 8];   // 16 KB
  __shared__ __align__(16) u16 pls[4][128 * 8]; // 8 KB, per-wave

  const int t    = threadIdx.x;
  const int wave = t >> 6, lane = t & 63;
  const int l16  = lane & 15, quad = lane >> 4;

  const int bid = blockIdx.x;
  const int js  = bid & 3, it = (bid >> 2) & 63, b = bid >> 8;
  const int i0  = it * 64;
  const int jbase = js * 1024;

  const u16* qTbh = qTh + ((size_t)b * 4096) * 16;
  const u16* qTbl = qTl + ((size_t)b * 4096) * 16;
  const u16* vb   = v + ((size_t)b * 128) * 4096;

  // A-frags: af_hl = [hi | lo] (quads 0,1 hi; 2,3 lo), af_h0 = [hi | 0]
  bf16x8 af_hl, af_h0 = {};
  {
    const int i = i0 + wave * 16 + l16;
    const u16* src = ((quad < 2) ? qTbh : qTbl) + (size_t)i * 16 + (quad & 1) * 8;
    *(uint4*)&af_hl = *(const uint4*)src;
    if (quad < 2) af_h0 = af_hl;
  }

  // V staging: piece p = t + 256k; src = v[c = (p>>7)*16 + (p&15)]
  //                                     [j = jbase + (p>>6 &1)*32 + (p>>4 &3)*8]
  const u16* vsrcB[4];
  u16* vdstB[4];
  #pragma unroll
  for (int k = 0; k < 4; ++k){
    const int p = t + 256 * k;
    const int c  = ((p >> 7) << 4) | (p & 15);
    const int jl = ((p >> 6) & 1) * 32 + ((p >> 4) & 3) * 8;
    vsrcB[k] = vb + (size_t)c * 4096 + jbase + jl;
    vdstB[k] = vls + ((size_t)(wave * 64 + 256 * k)) * 8;   // wave-uniform base
  }

  f32x4 oacc[8];
  #pragma unroll
  for (int cs = 0; cs < 8; ++cs){ oacc[cs][0]=0.f; oacc[cs][1]=0.f; oacc[cs][2]=0.f; oacc[cs][3]=0.f; }
  float m_run[4], l_run[4];
  #pragma unroll
  for (int r = 0; r < 4; ++r){ m_run[r] = -1e30f; l_run[r] = 0.f; }

  for (int ch = 0; ch < 16; ++ch){
    const int j0 = ch * 64;
    __syncthreads();   // prev chunk's vls reads complete
    #pragma unroll
    for (int k = 0; k < 4; ++k)
      gload_lds16(vsrcB[k] + j0, vdstB[k]);

    // QK^T: S = hi.hi + lo.hi + hi.lo via 2 MFMAs
    f32x4 sacc[4];
    #pragma unroll
    for (int ns = 0; ns < 4; ++ns){
      const int j = jbase + j0 + ns * 16 + l16;
      bf16x8 b_hh, b_ll;
      *(uint4*)&b_hh = *(const uint4*)(qTbh + (size_t)j * 16 + (quad & 1) * 8);
      *(uint4*)&b_ll = *(const uint4*)(qTbl + (size_t)j * 16 + (quad & 1) * 8);
      f32x4 z = {0.f, 0.f, 0.f, 0.f};
      z = __builtin_amdgcn_mfma_f32_16x16x32_bf16(af_hl, b_hh, z, 0, 0, 0);
      z = __builtin_amdgcn_mfma_f32_16x16x32_bf16(af_h0, b_ll, z, 0, 0, 0);
      sacc[ns] = z;
    }
    // online softmax per row (row = quad*4+r, cols ns*16+l16)
    float pv[4][4];
    #pragma unroll
    for (int r = 0; r < 4; ++r){
      float mx = fmaxf(fmaxf(sacc[0][r], sacc[1][r]), fmaxf(sacc[2][r], sacc[3][r]));
      mx = fmaxf(mx, __shfl_xor(mx, 1));
      mx = fmaxf(mx, __shfl_xor(mx, 2));
      mx = fmaxf(mx, __shfl_xor(mx, 4));
      mx = fmaxf(mx, __shfl_xor(mx, 8));
      const float mnew  = fmaxf(m_run[r], mx);
      const float alpha = __expf(m_run[r] - mnew);
      m_run[r] = mnew;
      float rs = 0.f;
      #pragma unroll
      for (int ns = 0; ns < 4; ++ns){
        pv[ns][r] = __expf(sacc[ns][r] - mnew);
        rs += pv[ns][r];
      }
      rs += __shfl_xor(rs, 1); rs += __shfl_xor(rs, 2);
      rs += __shfl_xor(rs, 4); rs += __shfl_xor(rs, 8);
      l_run[r] = l_run[r] * alpha + rs;
      #pragma unroll
      for (int cs = 0; cs < 8; ++cs) oacc[cs][r] *= alpha;
    }
    // P -> F-layout LDS: element (i=quad*4+r, jl=ns*16+l16) ->
    // piece = (ns>>1)*64 + ((ns*2 + (l16>>3))&3)*16 + i, slot jj = l16&7
    #pragma unroll
    for (int ns = 0; ns < 4; ++ns){
      const int ks = ns >> 1;
      const int qp = (ns * 2 + (l16 >> 3)) & 3;
      #pragma unroll
      for (int r = 0; r < 4; ++r)
        pls[wave][(ks * 64 + qp * 16 + quad * 4 + r) * 8 + (l16 & 7)] = f2b(pv[ns][r]);
    }
    __syncthreads();   // vls staged (vmcnt drained) + pls visible
    // PV: O[i][c] += P[i][j] V[j][c] — frag reads at base + lane*16 (no conflicts)
    #pragma unroll
    for (int ks = 0; ks < 2; ++ks){
      bf16x8 pf = *(const bf16x8*)(pls[wave] + ((ks * 64 + lane) << 3));
      #pragma unroll
      for (int cs = 0; cs < 8; ++cs){
        bf16x8 vf = *(const bf16x8*)(vls + (((cs * 2 + ks) * 64 + lane) << 3));
        oacc[cs] = __builtin_amdgcn_mfma_f32_16x16x32_bf16(pf, vf, oacc[cs], 0, 0, 0);
      }
    }
  }

  u16* pob = po + (size_t)bid * 64 * 128;
  #pragma unroll
  for (int cs = 0; cs < 8; ++cs)
    #pragma unroll
    for (int r = 0; r < 4; ++r)
      pob[(wave * 16 + quad * 4 + r) * 128 + cs * 16 + l16] = f2b(oacc[cs][r]);
  if (l16 == 0){
    #pragma unroll
    for (int r = 0; r < 4; ++r){
      pm[(size_t)bid * 64 + wave * 16 + quad * 4 + r] = m_run[r];
      pl[(size_t)bid * 64 + wave * 16 + quad * 4 + r] = l_run[r];
    }
  }
}

// ---------------------------------------------------------------------------
// PAM combine (pixel-major): merge 4 j-seg partials, gamma + residual,
// in-place over padded feat1_T. Grid 256 = b(4) x i-tile(64).
// ---------------------------------------------------------------------------
__global__ __launch_bounds__(256) void k_pam_comb2(
    const u16* __restrict__ po, const float* __restrict__ pm, const float* __restrict__ pl,
    const void* __restrict__ gptr, const int* __restrict__ flagp,
    u16* __restrict__ featT)
{
  __shared__ float wgt[4][64];
  const int t  = threadIdx.x;
  const int it = blockIdx.x & 63, b = blockIdx.x >> 6;
  const int base = (b * 64 + it) * 4;
  if (t < 64){
    const float m0 = pm[(size_t)(base+0)*64 + t];
    const float m1 = pm[(size_t)(base+1)*64 + t];
    const float m2 = pm[(size_t)(base+2)*64 + t];
    const float m3 = pm[(size_t)(base+3)*64 + t];
    const float M  = fmaxf(fmaxf(m0, m1), fmaxf(m2, m3));
    const float e0 = __expf(m0 - M), e1 = __expf(m1 - M);
    const float e2 = __expf(m2 - M), e3 = __expf(m3 - M);
    const float L  = pl[(size_t)(base+0)*64+t]*e0 + pl[(size_t)(base+1)*64+t]*e1
                   + pl[(size_t)(base+2)*64+t]*e2 + pl[(size_t)(base+3)*64+t]*e3;
    const float li = 1.0f / L;
    wgt[0][t] = e0*li; wgt[1][t] = e1*li; wgt[2][t] = e2*li; wgt[3][t] = e3*li;
  }
  __syncthreads();
  const float g = ldf(gptr, 0, *flagp);
  const int c = t & 127, ih = t >> 7;
  const int i0 = it * 64;
  for (int st = 0; st < 32; ++st){
    const int il = ih + st * 2;
    float acc = 0.f;
    #pragma unroll
    for (int s = 0; s < 4; ++s)
      acc += wgt[s][il] * b2f(po[((size_t)(base+s)*64 + il)*128 + c]);
    const int i = i0 + il;
    const int pix = (i >> 6) * 66 + (i & 63) + 67;
    u16* addr = featT + ((size_t)b * PPIX + pix) * 128 + c;
    *addr = f2b(g * acc + b2f(*addr));
  }
}

// ---------------------------------------------------------------------------
// CAM attention (channel-major feat2): writes attn bf16 [b][c][d] (row-major).
// ---------------------------------------------------------------------------
__global__ __launch_bounds__(128) void k_cam_attn(
    const u16* __restrict__ f, u16* __restrict__ attnc)
{
  __shared__ float fc[4096];
  __shared__ float red[128];
  const int d = threadIdx.x;
  const int c = blockIdx.x & 127, b = blockIdx.x >> 7;
  const u16* fb   = f + (size_t)b * 128 * HW;
  const u16* rowc = fb + (size_t)c * HW;
  for (int mi = d; mi < 4096; mi += 128) fc[mi] = b2f(rowc[mi]);
  __syncthreads();

  const u16* rowd = fb + (size_t)d * HW;
  float e = 0.f;
  for (int mm = 0; mm < 4096; mm += 8){
    const uint4 xv = *(const uint4*)(rowd + mm);
    const u16* px = (const u16*)&xv;
    #pragma unroll
    for (int k = 0; k < 8; ++k) e += fc[mm + k] * b2f(px[k]);
  }
  red[d] = e;
  __syncthreads();
  for (int st = 64; st > 0; st >>= 1){
    if (d < st) red[d] = fminf(red[d], red[d + st]);
    __syncthreads();
  }
  const float emin = red[0];
  __syncthreads();
  const float pd = __expf(emin - e);
  red[d] = pd;
  __syncthreads();
  for (int st = 64; st > 0; st >>= 1){
    if (d < st) red[d] += red[d + st];
    __syncthreads();
  }
  attnc[((size_t)b * 128 + c) * 128 + d] = f2b(pd / red[0]);
}

// ---------------------------------------------------------------------------
extern "C" void kernel_launch(void* const* d_in, const int* in_sizes, int n_in,
                              void* d_out, int out_size, void* d_ws, size_t ws_size,
                              hipStream_t stream)
{
  (void)in_sizes; (void)n_in; (void)out_size; (void)ws_size;

  const void* x    = d_in[0];
  const void* w11  = d_in[1];
  const void* g11  = d_in[2];
  const void* b11  = d_in[3];
  const void* m11  = d_in[4];
  const void* v11  = d_in[5];
  const void* w12  = d_in[6];
  const void* g12  = d_in[7];
  const void* b12  = d_in[8];
  const void* m12  = d_in[9];
  const void* v12  = d_in[10];
  const void* kw   = d_in[11];
  const void* kb   = d_in[12];
  const void* vw   = d_in[13];
  const void* vb   = d_in[14];
  const void* pgam = d_in[15];
  const void* cgam = d_in[16];
  const void* w21  = d_in[17];
  const void* g21  = d_in[18];
  const void* b21  = d_in[19];
  const void* m21  = d_in[20];
  const void* v21  = d_in[21];
  const void* w22  = d_in[22];
  const void* g22  = d_in[23];
  const void* b22  = d_in[24];
  const void* m22  = d_in[25];
  const void* v22  = d_in[26];
  const void* w31  = d_in[27];
  const void* b31  = d_in[28];
  const void* w32  = d_in[29];
  const void* b32  = d_in[30];
  const void* w4   = d_in[31];
  const void* b4   = d_in[32];

  char* wsb = (char*)d_ws;
  size_t off = 0;
  auto alloc = [&](size_t bytes) -> void* {
    void* pp = wsb + off;
    off += (bytes + 255) & ~(size_t)255;
    return pp;
  };
  u16*   xT      = (u16*)alloc((size_t)4 * PPIX * 512 * 2);  // dead after trunk -> po
  u16*   feat1T  = (u16*)alloc((size_t)4 * PPIX * 128 * 2);  // padded; later pa_feat (in-place)
  u16*   feat2T  = (u16*)alloc((size_t)4 * PPIX * 128 * 2);  // padded (residual reads)
  u16*   feat2cm = (u16*)alloc((size_t)4 * 128 * HW * 2);    // channel-major (CAM energy)
  u16*   cafeatT = (u16*)alloc((size_t)4 * PPIX * 128 * 2);  // padded
  u16*   vbuf    = (u16*)alloc((size_t)4 * 128 * HW * 2);    // v cm; later pa_conv_T (unpadded)
  u16*   caconvT = (u16*)alloc((size_t)4 * HW * 128 * 2);    // unpadded pixel-major
  u16*   qTh     = (u16*)alloc((size_t)4 * HW * 16 * 2);
  u16*   qTl     = (u16*)alloc((size_t)4 * HW * 16 * 2);
  float* pm      = (float*)alloc((size_t)1024 * 64 * 4);
  float* pl      = (float*)alloc((size_t)1024 * 64 * 4);
  u16*   attnc   = (u16*)alloc((size_t)4 * 128 * 128 * 2);
  float* scale   = (float*)alloc(512 * 4);
  float* shift   = (float*)alloc(512 * 4);
  u16*   w11r    = (u16*)alloc((size_t)128 * 4608 * 2);
  u16*   w12r    = (u16*)alloc((size_t)128 * 4608 * 2);
  u16*   w21r    = (u16*)alloc((size_t)128 * 1152 * 2);
  u16*   w22r    = (u16*)alloc((size_t)128 * 1152 * 2);
  u16*   kwb     = (u16*)alloc((size_t)16 * 128 * 2);
  u16*   vwb     = (u16*)alloc((size_t)128 * 128 * 2);
  u16*   w31b    = (u16*)alloc((size_t)64 * 128 * 2);
  u16*   w32b    = (u16*)alloc((size_t)64 * 128 * 2);
  u16*   w4b     = (u16*)alloc((size_t)64 * 128 * 2);
  int*   flag    = (int*)alloc(256);
  u16*   po      = xT;   // 16.8 MB <= xT's 17.8 MB; xT dead after trunk convs

  // prep
  k_detect<<<1, 512, 0, stream>>>((const u32*)x, flag);
  k_prep<<<1, 512, 0, stream>>>(g11,b11,m11,v11, g12,b12,m12,v12,
                                g21,b21,m21,v21, g22,b22,m22,v22, flag, scale, shift);
  k_halo<512><<<260, 256, 0, stream>>>(xT);
  k_halo<128><<<65, 256, 0, stream>>>(feat1T);
  k_halo<128><<<65, 256, 0, stream>>>(cafeatT);
  k_xT<<<1024, 256, 0, stream>>>(x, flag, xT);
  k_reorder_cvt<<<2304, 256, 0, stream>>>(w11, flag, w11r, 512);
  k_reorder_cvt<<<2304, 256, 0, stream>>>(w12, flag, w12r, 512);
  k_reorder_cvt<<<576, 256, 0, stream>>>(w21, flag, w21r, 128);
  k_reorder_cvt<<<576, 256, 0, stream>>>(w22, flag, w22r, 128);
  k_cvt<<<2, 256, 0, stream>>>(kw, flag, kwb, 16 * 128);
  k_cvt<<<16, 256, 0, stream>>>(vw, flag, vwb, 128 * 128);
  k_cvt<<<8, 256, 0, stream>>>(w31, flag, w31b, 64 * 128);
  k_cvt<<<8, 256, 0, stream>>>(w32, flag, w32b, 64 * 128);
  k_cvt<<<8, 256, 0, stream>>>(w4, flag, w4b, 64 * 128);

  // trunk convs, fused LDS-GEMM
  k_cgemm<512, true, true><<<256, 256, 0, stream>>>(
      xT, xT, w11r, w12r, scale, shift, feat1T, feat2T, feat2cm);

  // PAM
  k_convT<128,16,4,false,true,false,false><<<256,256,0,stream>>>(
      feat1T, nullptr, kwb, kb, flag, qTh, (float*)qTl);
  k_convT<128,128,2,false,true,false,false><<<2048,256,0,stream>>>(
      feat1T, nullptr, vwb, vb, flag, vbuf, nullptr);
  k_pam_flash<<<1024, 256, 0, stream>>>(qTh, qTl, vbuf, po, pm, pl);
  k_pam_comb2<<<256, 256, 0, stream>>>(po, pm, pl, pgam, flag, feat1T);  // -> pa_feat

  // CAM: attn (bf16 [c][d]) then MFMA GEMM attn @ f with residual epilogue
  k_cam_attn<<<512, 128, 0, stream>>>(feat2cm, attnc);
  k_convT<128,128,6,false,true,true,true><<<2048,256,0,stream>>>(
      feat2T, feat2T, attnc, cgam, flag, cafeatT, nullptr);

  // second convs, fused LDS-GEMM (unpadded pixel-major outputs)
  k_cgemm<128, false, false><<<256, 256, 0, stream>>>(
      feat1T, cafeatT, w21r, w22r, scale + 256, shift + 256, vbuf, caconvT, nullptr);

  // heads -> d_out [3][4][64][4096], channel-major, dtype per flag
  const size_t SEC = (size_t)4 * 64 * HW;
  u16*   outB = (u16*)d_out;
  float* outF = (float*)d_out;
  k_convT<128,64,3,false,false,false,false><<<1024,256,0,stream>>>(
      vbuf,    nullptr, w31b, b31, flag, outB,           outF);
  k_convT<128,64,3,false,false,false,false><<<1024,256,0,stream>>>(
      caconvT, nullptr, w32b, b32, flag, outB + SEC,     outF + SEC);
  k_convT<128,64,3,true ,false,false,false><<<1024,256,0,stream>>>(
      vbuf,    caconvT, w4b,  b4,  flag, outB + 2 * SEC, outF + 2 * SEC);
}

// Round 7
// 420.259 us; speedup vs baseline: 2.4554x; 1.1426x over previous
//
#include <hip/hip_runtime.h>
#include <stdint.h>

typedef unsigned short u16;
typedef unsigned int   u32;
typedef unsigned long long u64;
typedef __attribute__((ext_vector_type(8))) short bf16x8;
typedef __attribute__((ext_vector_type(4))) float f32x4;

#define DEV static __device__ __forceinline__

DEV float b2f(u16 u){ u32 x = ((u32)u) << 16; float f; __builtin_memcpy(&f, &x, 4); return f; }
DEV u16 f2b(float f){ u32 x; __builtin_memcpy(&x, &f, 4); return (u16)((x + 0x7fffu + ((x >> 16) & 1u)) >> 16); }
DEV u16 f2b_trunc(float f){ u32 x; __builtin_memcpy(&x, &f, 4); return (u16)(x >> 16); }
DEV float ldf(const void* p, int i, int flg){
  return flg ? b2f(((const u16*)p)[i]) : ((const float*)p)[i];
}
// async global->LDS, 16B per lane; LDS dest = wave-uniform base + lane*16
DEV void gload_lds16(const u16* g, u16* l){
  __builtin_amdgcn_global_load_lds((const __attribute__((address_space(1))) void*)g,
                                   (__attribute__((address_space(3))) void*)l, 16, 0, 0);
}

// Dims: B=4, H=W=64, HW=4096, Cin=512, Cm=128, Ck=16, Cout=64
// Padded pixel space: 66x66 = 4356, interior pixel (h,w) -> h*66+w+67
static constexpr int HW   = 4096;
static constexpr int PPIX = 4356;

// ---------------------------------------------------------------------------
// Fused dtype-detect + BN fold. Block 512. flag: 1=bf16 inputs, 0=fp32.
// ---------------------------------------------------------------------------
__global__ void k_prep(
    const u32* __restrict__ x,
    const void* g0,const void* b0,const void* m0,const void* v0,
    const void* g1,const void* b1,const void* m1,const void* v1,
    const void* g2,const void* b2,const void* m2,const void* v2,
    const void* g3,const void* b3,const void* m3,const void* v3,
    int* __restrict__ flag, float* scale, float* shift)
{
  __shared__ int cnt;
  __shared__ int sflag;
  const int t = threadIdx.x;
  if (t == 0) cnt = 0;
  __syncthreads();
  const u32 w  = x[t];
  const u32 eb = (w >> 7) & 0xFFu;         // bf16 exponent of the LOW half
  if (eb >= 100u && eb <= 150u) atomicAdd(&cnt, 1);
  __syncthreads();
  if (t == 0){ sflag = (cnt > 384) ? 1 : 0; *flag = sflag; }
  __syncthreads();
  const int flg = sflag;
  const int set = t >> 7, c = t & 127;
  const void *gp,*bp,*mp,*vp;
  if      (set == 0){gp=g0;bp=b0;mp=m0;vp=v0;}
  else if (set == 1){gp=g1;bp=b1;mp=m1;vp=v1;}
  else if (set == 2){gp=g2;bp=b2;mp=m2;vp=v2;}
  else              {gp=g3;bp=b3;mp=m3;vp=v3;}
  const float sc = ldf(gp,c,flg) * rsqrtf(ldf(vp,c,flg) + 1e-5f);
  scale[t] = sc;
  shift[t] = ldf(bp,c,flg) - ldf(mp,c,flg) * sc;
}

// ---------------------------------------------------------------------------
// 5 small weight converts in one launch. Group = 4 elements.
// kw [0,512) vw [512,4608) w31 [4608,6656) w32 [6656,8704) w4 [8704,10752)
// ---------------------------------------------------------------------------
__global__ void k_cvt5(
    const void* s0,const void* s1,const void* s2,const void* s3,const void* s4,
    const int* __restrict__ flagp,
    u16* d0,u16* d1,u16* d2,u16* d3,u16* d4)
{
  const int g = blockIdx.x * 256 + threadIdx.x;
  if (g >= 10752) return;
  const void* s; u16* d; int base;
  if      (g < 512) { s=s0; d=d0; base=0;    }
  else if (g < 4608){ s=s1; d=d1; base=512;  }
  else if (g < 6656){ s=s2; d=d2; base=4608; }
  else if (g < 8704){ s=s3; d=d3; base=6656; }
  else              { s=s4; d=d4; base=8704; }
  const int i = g - base;
  u64 ov;
  if (*flagp){
    ov = ((const u64*)s)[i];
  } else {
    const float4 f = ((const float4*)s)[i];
    const u16 a0 = f2b(f.x), a1 = f2b(f.y), a2 = f2b(f.z), a3 = f2b(f.w);
    ov = (u64)a0 | ((u64)a1 << 16) | ((u64)a2 << 32) | ((u64)a3 << 48);
  }
  ((u64*)d)[i] = ov;
}

// ---------------------------------------------------------------------------
// 4 3x3-weight reorders in one launch: [co][ci][rs] -> bf16 [co][rs][ci]
// ---------------------------------------------------------------------------
__global__ void k_reorder4(
    const void* w11,const void* w12,const void* w21,const void* w22,
    const int* __restrict__ flagp,
    u16* o11,u16* o12,u16* o21,u16* o22)
{
  int blk = blockIdx.x;
  const void* win; u16* wout; int cin;
  if      (blk < 2304){ win=w11; wout=o11; cin=512; }
  else if (blk < 4608){ win=w12; wout=o12; cin=512; blk-=2304; }
  else if (blk < 5184){ win=w21; wout=o21; cin=128; blk-=4608; }
  else                { win=w22; wout=o22; cin=128; blk-=5184; }
  const int idx = blk * 256 + threadIdx.x;
  const int flg = *flagp;
  const int n9 = cin * 9;
  const int co = idx / n9;
  const int rem = idx - co * n9;
  const int ci = rem / 9;
  const int rs = rem - ci * 9;
  const u16 v = flg ? ((const u16*)win)[idx] : f2b(((const float*)win)[idx]);
  wout[co * n9 + rs * cin + ci] = v;
}

// ---------------------------------------------------------------------------
// Zero halos of the 3 padded tensors in one launch.
// xT C=512 (260 blk), feat1T C=128 (65 blk), cafeatT C=128 (65 blk).
// ---------------------------------------------------------------------------
__global__ void k_halo3(u16* __restrict__ xT, u16* __restrict__ f1, u16* __restrict__ cf)
{
  int blk = blockIdx.x;
  u16* buf; int cmask, csh;
  if      (blk < 260){ buf = xT; cmask = 511; csh = 9; }
  else if (blk < 325){ buf = f1; cmask = 127; csh = 7; blk -= 260; }
  else               { buf = cf; cmask = 127; csh = 7; blk -= 325; }
  const int tid = blk * 256 + threadIdx.x;
  const int e  = tid * 8;
  const int cc = e & cmask;
  const int rem = e >> csh;
  const int hp = rem % 260;
  const int b  = rem / 260;
  int pix;
  if      (hp < 66)  pix = hp;
  else if (hp < 132) pix = 65 * 66 + (hp - 66);
  else if (hp < 196) pix = (hp - 132 + 1) * 66;
  else               pix = (hp - 196 + 1) * 66 + 65;
  uint4 z; z.x = 0; z.y = 0; z.z = 0; z.w = 0;
  *(uint4*)(buf + ((size_t)b * PPIX + pix) * (cmask + 1) + cc) = z;
}

// ---------------------------------------------------------------------------
// x transpose: [b][512][4096] (fp32 or bf16) -> padded bf16 [b][4356][512]
// ---------------------------------------------------------------------------
__global__ __launch_bounds__(256) void k_xT(
    const void* __restrict__ src, const int* __restrict__ flagp, u16* __restrict__ dst)
{
  const int t = threadIdx.x, wave = t >> 6, lane = t & 63;
  const int pb = blockIdx.x & 31, ct = (blockIdx.x >> 5) & 7, b = blockIdx.x >> 8;
  const int c  = ct * 64 + lane;
  const int p0 = pb * 128 + wave * 32;
  const size_t sbase = ((size_t)(b * 512) + c) * 4096 + p0;

  u16 vals[32];
  if (*flagp){
    const u16* s = (const u16*)src + sbase;
    #pragma unroll
    for (int k = 0; k < 4; ++k){
      uint4 v = *(const uint4*)(s + k * 8);
      __builtin_memcpy(&vals[k * 8], &v, 16);
    }
  } else {
    const float* s = (const float*)src + sbase;
    #pragma unroll
    for (int k = 0; k < 8; ++k){
      float4 v = *(const float4*)(s + k * 4);
      vals[k*4+0] = f2b(v.x); vals[k*4+1] = f2b(v.y);
      vals[k*4+2] = f2b(v.z); vals[k*4+3] = f2b(v.w);
    }
  }
  const int hrow = (p0 >> 6) * 66 + (p0 & 63) + 67;
  u16* d = dst + ((size_t)b * PPIX + hrow) * 512 + c;
  #pragma unroll
  for (int k = 0; k < 32; ++k) d[(size_t)k * 512] = vals[k];
}

// ---------------------------------------------------------------------------
// Fused sibling 3x3 convs as LDS-tiled implicit GEMM (m97 structure).
// ---------------------------------------------------------------------------
template<int CIN_, bool PADOUT_, bool DUALB_>
__global__ __launch_bounds__(256, 1) void k_cgemm(
    const u16* __restrict__ xA, const u16* __restrict__ xB,
    const u16* __restrict__ wA, const u16* __restrict__ wB,
    const float* __restrict__ scale, const float* __restrict__ shift,
    u16* __restrict__ outA, u16* __restrict__ outBp, u16* __restrict__ outB2)
{
  constexpr int K9   = 9 * CIN_;
  constexpr int NCH  = CIN_ / 64;
  constexpr int OPIX = PADOUT_ ? PPIX : 4096;

  __shared__ __align__(16) u16 At[128 * 64];
  __shared__ __align__(16) u16 Bt[128 * 64];

  const int t = threadIdx.x;
  const int w = t >> 6, lane = t & 63;
  const int l16 = lane & 15, quad = lane >> 4;

  const int cid = blockIdx.x >> 7;
  const int t7  = blockIdx.x & 127;
  const int b   = t7 >> 5;
  const int p0  = (t7 & 31) << 7;

  const u16* xin = cid ? xB : xA;
  const u16* wK  = cid ? wB : wA;
  const float* sc = scale + cid * 128;
  const float* sh = shift + cid * 128;

  const int rowS = t >> 3;
  const int sw   = ((t & 7) ^ (rowS & 7)) << 3;

  const u16* gA[4]; const u16* gB[4];
  u16* lA[4]; u16* lB[4];
  #pragma unroll
  for (int k = 0; k < 4; ++k){
    const int rA = k * 32 + rowS;
    gA[k] = wK + (size_t)rA * K9 + sw;
    const int px = p0 + k * 32 + rowS;
    const int h = px >> 6, wc = px & 63;
    gB[k] = xin + ((size_t)b * PPIX + h * 66 + wc) * CIN_ + sw;
    lA[k] = At + k * 2048 + w * 512;
    lB[k] = Bt + k * 2048 + w * 512;
  }

  f32x4 acc[4][4];
  #pragma unroll
  for (int mi = 0; mi < 4; ++mi)
    #pragma unroll
    for (int ni = 0; ni < 4; ++ni){
      acc[mi][ni][0]=0.f; acc[mi][ni][1]=0.f; acc[mi][ni][2]=0.f; acc[mi][ni][3]=0.f;
    }

  const int wc4 = (w >> 1) << 6;
  const int wp4 = (w & 1) << 6;

  #pragma unroll 1
  for (int tap = 0; tap < 9; ++tap){
    const int tb = (tap / 3) * 66 + (tap % 3);
    #pragma unroll 1
    for (int cc = 0; cc < NCH; ++cc){
      const int offA = tap * CIN_ + cc * 64;
      const int offB = tb  * CIN_ + cc * 64;
      #pragma unroll
      for (int k = 0; k < 4; ++k){
        gload_lds16(gA[k] + offA, lA[k]);
        gload_lds16(gB[k] + offB, lB[k]);
      }
      __syncthreads();
      #pragma unroll
      for (int ks = 0; ks < 2; ++ks){
        bf16x8 af[4], bf[4];
        const int col = ((ks * 4 + quad) ^ (l16 & 7)) << 3;
        #pragma unroll
        for (int mi = 0; mi < 4; ++mi)
          af[mi] = *(const bf16x8*)(At + ((wc4 + mi * 16 + l16) << 6) + col);
        #pragma unroll
        for (int ni = 0; ni < 4; ++ni)
          bf[ni] = *(const bf16x8*)(Bt + ((wp4 + ni * 16 + l16) << 6) + col);
        #pragma unroll
        for (int mi = 0; mi < 4; ++mi)
          #pragma unroll
          for (int ni = 0; ni < 4; ++ni)
            acc[mi][ni] = __builtin_amdgcn_mfma_f32_16x16x32_bf16(af[mi], bf[ni], acc[mi][ni], 0, 0, 0);
      }
      __syncthreads();
    }
  }

  u16* outp = cid ? outBp : outA;
  #pragma unroll
  for (int mi = 0; mi < 4; ++mi){
    #pragma unroll
    for (int ni = 0; ni < 4; ++ni){
      const int px = p0 + wp4 + ni * 16 + l16;
      const int opix = PADOUT_ ? ((px >> 6) * 66 + (px & 63) + 67) : px;
      const int co4 = wc4 + mi * 16 + quad * 4;
      u16 pk[4];
      #pragma unroll
      for (int rr = 0; rr < 4; ++rr)
        pk[rr] = f2b(fmaxf(acc[mi][ni][rr] * sc[co4 + rr] + sh[co4 + rr], 0.f));
      u64 pkv; __builtin_memcpy(&pkv, pk, 8);
      *(u64*)(outp + ((size_t)b * OPIX + opix) * 128 + co4) = pkv;
      if constexpr (DUALB_){
        if (cid){
          #pragma unroll
          for (int rr = 0; rr < 4; ++rr)
            outB2[((size_t)(b * 128) + co4 + rr) * 4096 + px] = pk[rr];
        }
      }
    }
  }
}

// ---------------------------------------------------------------------------
// 1x1 conv (MFMA), one wave per 16(co) x 16(px) tile; pixel-major input.
// EPI: 2 = +bias -> channel-major bf16
//      3 = +bias -> flag ? bf16 : fp32, channel-major (d_out heads)
//      4 = +bias -> qT hi/lo bf16 pair [b][4096][16]
//      6 = CAM: gamma*acc + residual(xin2, padded pixel-major) -> padded pm out
// WPB_: weights indexed per batch (wK + b*CO*K) — used for CAM attn GEMM.
// ---------------------------------------------------------------------------
template<int CIN_, int CO_, int EPI_, bool SUM2_, bool PADIN_, bool PADOUT_, bool WPB_>
__global__ __launch_bounds__(256) void k_convT(
    const u16* __restrict__ xin, const u16* __restrict__ xin2,
    const u16* __restrict__ wK,
    const void* __restrict__ bias, const int* __restrict__ flagp,
    u16* __restrict__ outB, float* __restrict__ outF)
{
  constexpr int K    = CIN_;
  constexpr int MT   = CO_ / 16;
  constexpr int IPIX = PADIN_ ? PPIX : 4096;
  constexpr int OPIX = PADOUT_ ? PPIX : 4096;

  const int tid  = threadIdx.x;
  const int wave = tid >> 6;
  const int lane = tid & 63;
  const int l16  = lane & 15;
  const int quad = lane >> 4;

  int tile = blockIdx.x * 4 + wave;
  const int nt = tile & 255; tile >>= 8;
  const int mt = tile % MT;
  const int b  = tile / MT;

  const int p = nt * 16 + l16;
  const int h = p >> 6, wc = p & 63;

  const u16* wrow = wK + (WPB_ ? (size_t)b * CO_ * K : 0)
                       + (size_t)(mt * 16 + l16) * K + quad * 8;
  const u16* xb   = xin + (size_t)b * IPIX * CIN_ + quad * 8;

  f32x4 acc = {0.f, 0.f, 0.f, 0.f};

  const int poff = PADIN_ ? (h * 66 + wc + 67) : p;
  const u16* xrs = xb + (size_t)poff * CIN_;
  const u16* xrs2 = nullptr;
  if constexpr (SUM2_) xrs2 = xin2 + (size_t)b * IPIX * CIN_ + quad * 8 + (size_t)poff * CIN_;
  #pragma unroll
  for (int ci0 = 0; ci0 < CIN_; ci0 += 32){
    bf16x8 af = *(const bf16x8*)(wrow + ci0);
    bf16x8 bf;
    if constexpr (SUM2_){
      bf16x8 b1 = *(const bf16x8*)(xrs + ci0);
      bf16x8 b2 = *(const bf16x8*)(xrs2 + ci0);
      #pragma unroll
      for (int j = 0; j < 8; ++j)
        bf[j] = (short)f2b(b2f((u16)b1[j]) + b2f((u16)b2[j]));
    } else {
      bf = *(const bf16x8*)(xrs + ci0);
    }
    acc = __builtin_amdgcn_mfma_f32_16x16x32_bf16(af, bf, acc, 0, 0, 0);
  }

  const int flg = *flagp;

  if constexpr (EPI_ == 4){
    #pragma unroll
    for (int rr = 0; rr < 4; ++rr){
      const int co = quad * 4 + rr;   // MT == 1
      const float vv = acc[rr] + ldf(bias, co, flg);
      const u16 hb = f2b(vv);
      const float lo = vv - b2f(hb);
      const size_t qaddr = ((size_t)b * 4096 + p) * 16 + co;
      outB[qaddr] = hb;
      ((u16*)outF)[qaddr] = f2b(lo);
    }
  } else if constexpr (EPI_ == 6){
    const float g = ldf(bias, 0, flg);
    const int opix = PADOUT_ ? (h * 66 + wc + 67) : p;
    const int co4 = mt * 16 + quad * 4;
    const size_t addr = ((size_t)b * OPIX + opix) * CO_ + co4;
    u64 rv = *(const u64*)(xin2 + (size_t)b * OPIX * CO_ + (size_t)opix * CO_ + co4);
    u16 rk[4]; __builtin_memcpy(rk, &rv, 8);
    u16 pk[4];
    #pragma unroll
    for (int rr = 0; rr < 4; ++rr)
      pk[rr] = f2b(g * acc[rr] + b2f(rk[rr]));
    u64 pkv; __builtin_memcpy(&pkv, pk, 8);
    *(u64*)(outB + addr) = pkv;
  } else {
    #pragma unroll
    for (int rr = 0; rr < 4; ++rr){
      const int co = mt * 16 + quad * 4 + rr;
      const float vv = acc[rr] + ldf(bias, co, flg);
      const size_t addr = ((size_t)(b * CO_) + co) * 4096 + p;
      if constexpr (EPI_ == 2) outB[addr] = f2b(vv);
      else { if (flg) outB[addr] = f2b(vv); else outF[addr] = vv; }
    }
  }
}

// ---------------------------------------------------------------------------
// PAM flash attention v3: TWO-PASS. Pass A computes per-row segment max
// (hi-only QK, per-lane running max, ONE shuffle-reduce per block); pass B
// does exp(S-m) with zero online-softmax state: no rescale, no l-shuffles.
// l comes free from MFMA via a constant ones V-fragment.
// Grid 1024 = b x 64 i-tile x 4 j-seg. Block 256 = 4 waves.
// ---------------------------------------------------------------------------
__global__ __launch_bounds__(256) void k_pam_flash(
    const u16* __restrict__ qTh, const u16* __restrict__ qTl,
    const u16* __restrict__ v,
    u16* __restrict__ po, float* __restrict__ pm, float* __restrict__ pl)
{
  // F-layout: piece p = (cs*2+ks)*64 + lane, 8 u16 each; reads = base + lane*16B
  __shared__ __align__(16) u16 vls[1024 * 8];   // 16 KB
  __shared__ __align__(16) u16 pls[4][128 * 8]; // 8 KB, per-wave

  const int t    = threadIdx.x;
  const int wave = t >> 6, lane = t & 63;
  const int l16  = lane & 15, quad = lane >> 4;

  const int bid = blockIdx.x;
  const int js  = bid & 3, it = (bid >> 2) & 63, b = bid >> 8;
  const int i0  = it * 64;
  const int jbase = js * 1024;

  const u16* qTbh = qTh + ((size_t)b * 4096) * 16;
  const u16* qTbl = qTl + ((size_t)b * 4096) * 16;
  const u16* vb   = v + ((size_t)b * 128) * 4096;

  // A-frags: af_hl = [hi | lo] (quads 0,1 hi; 2,3 lo), af_h0 = [hi | 0]
  bf16x8 af_hl, af_h0 = {};
  {
    const int i = i0 + wave * 16 + l16;
    const u16* src = ((quad < 2) ? qTbh : qTbl) + (size_t)i * 16 + (quad & 1) * 8;
    *(uint4*)&af_hl = *(const uint4*)src;
    if (quad < 2) af_h0 = af_hl;
  }

  // ---- Pass A: segment row max (approx: S_A = hi.hi + lo.hi; off by the
  // tiny hi.lo term vs pass B -> exp(S_B - m) <= e^eps, no overflow) ----
  float mloc[4] = {-3e38f, -3e38f, -3e38f, -3e38f};
  #pragma unroll 1
  for (int ch = 0; ch < 16; ++ch){
    #pragma unroll
    for (int ns = 0; ns < 4; ++ns){
      const int j = jbase + ch * 64 + ns * 16 + l16;
      bf16x8 bh;
      *(uint4*)&bh = *(const uint4*)(qTbh + (size_t)j * 16 + (quad & 1) * 8);
      f32x4 z = {0.f, 0.f, 0.f, 0.f};
      z = __builtin_amdgcn_mfma_f32_16x16x32_bf16(af_hl, bh, z, 0, 0, 0);
      #pragma unroll
      for (int r = 0; r < 4; ++r) mloc[r] = fmaxf(mloc[r], z[r]);
    }
  }
  float mrow[4];
  #pragma unroll
  for (int r = 0; r < 4; ++r){
    float mm = mloc[r];
    mm = fmaxf(mm, __shfl_xor(mm, 1));
    mm = fmaxf(mm, __shfl_xor(mm, 2));
    mm = fmaxf(mm, __shfl_xor(mm, 4));
    mm = fmaxf(mm, __shfl_xor(mm, 8));
    mrow[r] = mm;
  }

  // V staging pointers (F-layout pieces)
  const u16* vsrcB[4];
  u16* vdstB[4];
  #pragma unroll
  for (int k = 0; k < 4; ++k){
    const int p = t + 256 * k;
    const int c  = ((p >> 7) << 4) | (p & 15);
    const int jl = ((p >> 6) & 1) * 32 + ((p >> 4) & 3) * 8;
    vsrcB[k] = vb + (size_t)c * 4096 + jbase + jl;
    vdstB[k] = vls + ((size_t)(wave * 64 + 256 * k)) * 8;
  }

  const short oneb = (short)0x3F80;   // bf16 1.0
  const bf16x8 vones = {oneb,oneb,oneb,oneb,oneb,oneb,oneb,oneb};

  f32x4 oacc[8];
  #pragma unroll
  for (int cs = 0; cs < 8; ++cs){ oacc[cs][0]=0.f; oacc[cs][1]=0.f; oacc[cs][2]=0.f; oacc[cs][3]=0.f; }
  f32x4 lacc = {0.f, 0.f, 0.f, 0.f};

  // ---- Pass B ----
  #pragma unroll 1
  for (int ch = 0; ch < 16; ++ch){
    const int j0 = ch * 64;
    __syncthreads();   // prev chunk's vls reads complete
    #pragma unroll
    for (int k = 0; k < 4; ++k)
      gload_lds16(vsrcB[k] + j0, vdstB[k]);

    #pragma unroll
    for (int ns = 0; ns < 4; ++ns){
      const int j = jbase + j0 + ns * 16 + l16;
      bf16x8 bh, bl;
      *(uint4*)&bh = *(const uint4*)(qTbh + (size_t)j * 16 + (quad & 1) * 8);
      *(uint4*)&bl = *(const uint4*)(qTbl + (size_t)j * 16 + (quad & 1) * 8);
      f32x4 z = {0.f, 0.f, 0.f, 0.f};
      z = __builtin_amdgcn_mfma_f32_16x16x32_bf16(af_hl, bh, z, 0, 0, 0);
      z = __builtin_amdgcn_mfma_f32_16x16x32_bf16(af_h0, bl, z, 0, 0, 0);
      const int ks = ns >> 1;
      const int qp = (ns * 2 + (l16 >> 3)) & 3;
      #pragma unroll
      for (int r = 0; r < 4; ++r){
        const float p = __expf(z[r] - mrow[r]);
        pls[wave][(ks * 64 + qp * 16 + quad * 4 + r) * 8 + (l16 & 7)] = f2b_trunc(p);
      }
    }
    __syncthreads();   // vls staged + pls visible
    #pragma unroll
    for (int ks = 0; ks < 2; ++ks){
      bf16x8 pf = *(const bf16x8*)(pls[wave] + ((ks * 64 + lane) << 3));
      #pragma unroll
      for (int cs = 0; cs < 8; ++cs){
        bf16x8 vf = *(const bf16x8*)(vls + (((cs * 2 + ks) * 64 + lane) << 3));
        oacc[cs] = __builtin_amdgcn_mfma_f32_16x16x32_bf16(pf, vf, oacc[cs], 0, 0, 0);
      }
      lacc = __builtin_amdgcn_mfma_f32_16x16x32_bf16(pf, vones, lacc, 0, 0, 0);
    }
  }

  u16* pob = po + (size_t)bid * 64 * 128;
  #pragma unroll
  for (int cs = 0; cs < 8; ++cs)
    #pragma unroll
    for (int r = 0; r < 4; ++r)
      pob[(wave * 16 + quad * 4 + r) * 128 + cs * 16 + l16] = f2b(oacc[cs][r]);
  if (l16 == 0){
    #pragma unroll
    for (int r = 0; r < 4; ++r){
      pm[(size_t)bid * 64 + wave * 16 + quad * 4 + r] = mrow[r];
      pl[(size_t)bid * 64 + wave * 16 + quad * 4 + r] = lacc[r];
    }
  }
}

// ---------------------------------------------------------------------------
// PAM combine (pixel-major): merge 4 j-seg partials, gamma + residual,
// in-place over padded feat1_T. Grid 256 = b(4) x i-tile(64).
// ---------------------------------------------------------------------------
__global__ __launch_bounds__(256) void k_pam_comb2(
    const u16* __restrict__ po, const float* __restrict__ pm, const float* __restrict__ pl,
    const void* __restrict__ gptr, const int* __restrict__ flagp,
    u16* __restrict__ featT)
{
  __shared__ float wgt[4][64];
  const int t  = threadIdx.x;
  const int it = blockIdx.x & 63, b = blockIdx.x >> 6;
  const int base = (b * 64 + it) * 4;
  if (t < 64){
    const float m0 = pm[(size_t)(base+0)*64 + t];
    const float m1 = pm[(size_t)(base+1)*64 + t];
    const float m2 = pm[(size_t)(base+2)*64 + t];
    const float m3 = pm[(size_t)(base+3)*64 + t];
    const float M  = fmaxf(fmaxf(m0, m1), fmaxf(m2, m3));
    const float e0 = __expf(m0 - M), e1 = __expf(m1 - M);
    const float e2 = __expf(m2 - M), e3 = __expf(m3 - M);
    const float L  = pl[(size_t)(base+0)*64+t]*e0 + pl[(size_t)(base+1)*64+t]*e1
                   + pl[(size_t)(base+2)*64+t]*e2 + pl[(size_t)(base+3)*64+t]*e3;
    const float li = 1.0f / L;
    wgt[0][t] = e0*li; wgt[1][t] = e1*li; wgt[2][t] = e2*li; wgt[3][t] = e3*li;
  }
  __syncthreads();
  const float g = ldf(gptr, 0, *flagp);
  const int c = t & 127, ih = t >> 7;
  const int i0 = it * 64;
  for (int st = 0; st < 32; ++st){
    const int il = ih + st * 2;
    float acc = 0.f;
    #pragma unroll
    for (int s = 0; s < 4; ++s)
      acc += wgt[s][il] * b2f(po[((size_t)(base+s)*64 + il)*128 + c]);
    const int i = i0 + il;
    const int pix = (i >> 6) * 66 + (i & 63) + 67;
    u16* addr = featT + ((size_t)b * PPIX + pix) * 128 + c;
    *addr = f2b(g * acc + b2f(*addr));
  }
}

// ---------------------------------------------------------------------------
// CAM energy + softmax via MFMA: E = f.f^T (128x128, K=4096 per batch),
// attn[c][d] = exp(minE_c - E_cd)/sum_d. Grid 32 = b(4) x ct(8); block 256.
// Wave w computes E[16c x 32d] (2 n-tiles); softmax via LDS.
// ---------------------------------------------------------------------------
__global__ __launch_bounds__(256) void k_cam_energy(
    const u16* __restrict__ f, u16* __restrict__ attnc)
{
  __shared__ float els[16][132];
  const int t = threadIdx.x, wave = t >> 6, lane = t & 63;
  const int l16 = lane & 15, quad = lane >> 4;
  const int ct = blockIdx.x & 7, b = blockIdx.x >> 3;
  const u16* fb = f + (size_t)b * 128 * 4096;
  const int c0 = ct * 16;
  const int d0 = wave * 32;

  f32x4 e0 = {0.f,0.f,0.f,0.f}, e1 = {0.f,0.f,0.f,0.f};
  #pragma unroll 2
  for (int k0 = 0; k0 < 4096; k0 += 32){
    bf16x8 afr, bf0, bf1;
    *(uint4*)&afr = *(const uint4*)(fb + (size_t)(c0 + l16) * 4096 + k0 + quad * 8);
    *(uint4*)&bf0 = *(const uint4*)(fb + (size_t)(d0 + l16) * 4096 + k0 + quad * 8);
    *(uint4*)&bf1 = *(const uint4*)(fb + (size_t)(d0 + 16 + l16) * 4096 + k0 + quad * 8);
    e0 = __builtin_amdgcn_mfma_f32_16x16x32_bf16(afr, bf0, e0, 0, 0, 0);
    e1 = __builtin_amdgcn_mfma_f32_16x16x32_bf16(afr, bf1, e1, 0, 0, 0);
  }
  #pragma unroll
  for (int r = 0; r < 4; ++r){
    els[quad * 4 + r][d0 + l16]      = e0[r];
    els[quad * 4 + r][d0 + 16 + l16] = e1[r];
  }
  __syncthreads();
  // softmax: thread (c = wave*4+quad, sg = l16) handles 8 d
  const int c = wave * 4 + quad, sg = l16;
  float mn = 3e38f;
  float ev[8];
  #pragma unroll
  for (int k = 0; k < 8; ++k){ ev[k] = els[c][sg * 8 + k]; mn = fminf(mn, ev[k]); }
  mn = fminf(mn, __shfl_xor(mn, 1));
  mn = fminf(mn, __shfl_xor(mn, 2));
  mn = fminf(mn, __shfl_xor(mn, 4));
  mn = fminf(mn, __shfl_xor(mn, 8));
  float s = 0.f;
  #pragma unroll
  for (int k = 0; k < 8; ++k){ ev[k] = __expf(mn - ev[k]); s += ev[k]; }
  s += __shfl_xor(s, 1); s += __shfl_xor(s, 2);
  s += __shfl_xor(s, 4); s += __shfl_xor(s, 8);
  const float inv = 1.0f / s;
  u16* dst = attnc + ((size_t)b * 128 + c0 + c) * 128 + sg * 8;
  #pragma unroll
  for (int k = 0; k < 8; ++k) dst[k] = f2b(ev[k] * inv);
}

// ---------------------------------------------------------------------------
extern "C" void kernel_launch(void* const* d_in, const int* in_sizes, int n_in,
                              void* d_out, int out_size, void* d_ws, size_t ws_size,
                              hipStream_t stream)
{
  (void)in_sizes; (void)n_in; (void)out_size; (void)ws_size;

  const void* x    = d_in[0];
  const void* w11  = d_in[1];
  const void* g11  = d_in[2];
  const void* b11  = d_in[3];
  const void* m11  = d_in[4];
  const void* v11  = d_in[5];
  const void* w12  = d_in[6];
  const void* g12  = d_in[7];
  const void* b12  = d_in[8];
  const void* m12  = d_in[9];
  const void* v12  = d_in[10];
  const void* kw   = d_in[11];
  const void* kb   = d_in[12];
  const void* vw   = d_in[13];
  const void* vb   = d_in[14];
  const void* pgam = d_in[15];
  const void* cgam = d_in[16];
  const void* w21  = d_in[17];
  const void* g21  = d_in[18];
  const void* b21  = d_in[19];
  const void* m21  = d_in[20];
  const void* v21  = d_in[21];
  const void* w22  = d_in[22];
  const void* g22  = d_in[23];
  const void* b22  = d_in[24];
  const void* m22  = d_in[25];
  const void* v22  = d_in[26];
  const void* w31  = d_in[27];
  const void* b31  = d_in[28];
  const void* w32  = d_in[29];
  const void* b32  = d_in[30];
  const void* w4   = d_in[31];
  const void* b4   = d_in[32];

  char* wsb = (char*)d_ws;
  size_t off = 0;
  auto alloc = [&](size_t bytes) -> void* {
    void* pp = wsb + off;
    off += (bytes + 255) & ~(size_t)255;
    return pp;
  };
  u16*   xT      = (u16*)alloc((size_t)4 * PPIX * 512 * 2);  // dead after trunk -> po
  u16*   feat1T  = (u16*)alloc((size_t)4 * PPIX * 128 * 2);  // padded; later pa_feat (in-place)
  u16*   feat2T  = (u16*)alloc((size_t)4 * PPIX * 128 * 2);  // padded (residual reads)
  u16*   feat2cm = (u16*)alloc((size_t)4 * 128 * HW * 2);    // channel-major (CAM energy)
  u16*   cafeatT = (u16*)alloc((size_t)4 * PPIX * 128 * 2);  // padded
  u16*   vbuf    = (u16*)alloc((size_t)4 * 128 * HW * 2);    // v cm; later pa_conv_T (unpadded)
  u16*   caconvT = (u16*)alloc((size_t)4 * HW * 128 * 2);    // unpadded pixel-major
  u16*   qTh     = (u16*)alloc((size_t)4 * HW * 16 * 2);
  u16*   qTl     = (u16*)alloc((size_t)4 * HW * 16 * 2);
  float* pm      = (float*)alloc((size_t)1024 * 64 * 4);
  float* pl      = (float*)alloc((size_t)1024 * 64 * 4);
  u16*   attnc   = (u16*)alloc((size_t)4 * 128 * 128 * 2);
  float* scale   = (float*)alloc(512 * 4);
  float* shift   = (float*)alloc(512 * 4);
  u16*   w11r    = (u16*)alloc((size_t)128 * 4608 * 2);
  u16*   w12r    = (u16*)alloc((size_t)128 * 4608 * 2);
  u16*   w21r    = (u16*)alloc((size_t)128 * 1152 * 2);
  u16*   w22r    = (u16*)alloc((size_t)128 * 1152 * 2);
  u16*   kwb     = (u16*)alloc((size_t)16 * 128 * 2);
  u16*   vwb     = (u16*)alloc((size_t)128 * 128 * 2);
  u16*   w31b    = (u16*)alloc((size_t)64 * 128 * 2);
  u16*   w32b    = (u16*)alloc((size_t)64 * 128 * 2);
  u16*   w4b     = (u16*)alloc((size_t)64 * 128 * 2);
  int*   flag    = (int*)alloc(256);
  u16*   po      = xT;   // 16.8 MB <= xT's 17.8 MB; xT dead after trunk convs

  // prep (4 launches)
  k_prep<<<1, 512, 0, stream>>>((const u32*)x,
                                g11,b11,m11,v11, g12,b12,m12,v12,
                                g21,b21,m21,v21, g22,b22,m22,v22, flag, scale, shift);
  k_halo3<<<390, 256, 0, stream>>>(xT, feat1T, cafeatT);
  k_xT<<<1024, 256, 0, stream>>>(x, flag, xT);
  k_reorder4<<<5760, 256, 0, stream>>>(w11, w12, w21, w22, flag, w11r, w12r, w21r, w22r);
  k_cvt5<<<42, 256, 0, stream>>>(kw, vw, w31, w32, w4, flag, kwb, vwb, w31b, w32b, w4b);

  // trunk convs, fused LDS-GEMM
  k_cgemm<512, true, true><<<256, 256, 0, stream>>>(
      xT, xT, w11r, w12r, scale, shift, feat1T, feat2T, feat2cm);

  // PAM
  k_convT<128,16,4,false,true,false,false><<<256,256,0,stream>>>(
      feat1T, nullptr, kwb, kb, flag, qTh, (float*)qTl);
  k_convT<128,128,2,false,true,false,false><<<2048,256,0,stream>>>(
      feat1T, nullptr, vwb, vb, flag, vbuf, nullptr);
  k_pam_flash<<<1024, 256, 0, stream>>>(qTh, qTl, vbuf, po, pm, pl);
  k_pam_comb2<<<256, 256, 0, stream>>>(po, pm, pl, pgam, flag, feat1T);  // -> pa_feat

  // CAM: MFMA energy+softmax, then MFMA GEMM attn @ f with residual epilogue
  k_cam_energy<<<32, 256, 0, stream>>>(feat2cm, attnc);
  k_convT<128,128,6,false,true,true,true><<<2048,256,0,stream>>>(
      feat2T, feat2T, attnc, cgam, flag, cafeatT, nullptr);

  // second convs, fused LDS-GEMM (unpadded pixel-major outputs)
  k_cgemm<128, false, false><<<256, 256, 0, stream>>>(
      feat1T, cafeatT, w21r, w22r, scale + 256, shift + 256, vbuf, caconvT, nullptr);

  // heads -> d_out [3][4][64][4096], channel-major, dtype per flag
  const size_t SEC = (size_t)4 * 64 * HW;
  u16*   outB = (u16*)d_out;
  float* outF = (float*)d_out;
  k_convT<128,64,3,false,false,false,false><<<1024,256,0,stream>>>(
      vbuf,    nullptr, w31b, b31, flag, outB,           outF);
  k_convT<128,64,3,false,false,false,false><<<1024,256,0,stream>>>(
      caconvT, nullptr, w32b, b32, flag, outB + SEC,     outF + SEC);
  k_convT<128,64,3,true ,false,false,false><<<1024,256,0,stream>>>(
      vbuf,    caconvT, w4b,  b4,  flag, outB + 2 * SEC, outF + 2 * SEC);
}

// Round 8
// 403.966 us; speedup vs baseline: 2.5545x; 1.0403x over previous
//
#include <hip/hip_runtime.h>
#include <stdint.h>

typedef unsigned short u16;
typedef unsigned int   u32;
typedef unsigned long long u64;
typedef __attribute__((ext_vector_type(8))) short bf16x8;
typedef __attribute__((ext_vector_type(4))) float f32x4;

#define DEV static __device__ __forceinline__

DEV float b2f(u16 u){ u32 x = ((u32)u) << 16; float f; __builtin_memcpy(&f, &x, 4); return f; }
DEV u16 f2b(float f){ u32 x; __builtin_memcpy(&x, &f, 4); return (u16)((x + 0x7fffu + ((x >> 16) & 1u)) >> 16); }
DEV u16 f2b_trunc(float f){ u32 x; __builtin_memcpy(&x, &f, 4); return (u16)(x >> 16); }
DEV float ldf(const void* p, int i, int flg){
  return flg ? b2f(((const u16*)p)[i]) : ((const float*)p)[i];
}
// async global->LDS, 16B per lane; LDS dest = wave-uniform base + lane*16
DEV void gload_lds16(const u16* g, u16* l){
  __builtin_amdgcn_global_load_lds((const __attribute__((address_space(1))) void*)g,
                                   (__attribute__((address_space(3))) void*)l, 16, 0, 0);
}

// Dims: B=4, H=W=64, HW=4096, Cin=512, Cm=128, Ck=16, Cout=64
// Padded pixel space: 66x66 = 4356, interior pixel (h,w) -> h*66+w+67
static constexpr int HW   = 4096;
static constexpr int PPIX = 4356;

// ---------------------------------------------------------------------------
// Fused dtype-detect + BN fold. Block 512. flag: 1=bf16 inputs, 0=fp32.
// ---------------------------------------------------------------------------
__global__ void k_prep(
    const u32* __restrict__ x,
    const void* g0,const void* b0,const void* m0,const void* v0,
    const void* g1,const void* b1,const void* m1,const void* v1,
    const void* g2,const void* b2,const void* m2,const void* v2,
    const void* g3,const void* b3,const void* m3,const void* v3,
    int* __restrict__ flag, float* scale, float* shift)
{
  __shared__ int cnt;
  __shared__ int sflag;
  const int t = threadIdx.x;
  if (t == 0) cnt = 0;
  __syncthreads();
  const u32 w  = x[t];
  const u32 eb = (w >> 7) & 0xFFu;         // bf16 exponent of the LOW half
  if (eb >= 100u && eb <= 150u) atomicAdd(&cnt, 1);
  __syncthreads();
  if (t == 0){ sflag = (cnt > 384) ? 1 : 0; *flag = sflag; }
  __syncthreads();
  const int flg = sflag;
  const int set = t >> 7, c = t & 127;
  const void *gp,*bp,*mp,*vp;
  if      (set == 0){gp=g0;bp=b0;mp=m0;vp=v0;}
  else if (set == 1){gp=g1;bp=b1;mp=m1;vp=v1;}
  else if (set == 2){gp=g2;bp=b2;mp=m2;vp=v2;}
  else              {gp=g3;bp=b3;mp=m3;vp=v3;}
  const float sc = ldf(gp,c,flg) * rsqrtf(ldf(vp,c,flg) + 1e-5f);
  scale[t] = sc;
  shift[t] = ldf(bp,c,flg) - ldf(mp,c,flg) * sc;
}

// ---------------------------------------------------------------------------
// 5 small weight converts in one launch. Group = 4 elements.
// ---------------------------------------------------------------------------
__global__ void k_cvt5(
    const void* s0,const void* s1,const void* s2,const void* s3,const void* s4,
    const int* __restrict__ flagp,
    u16* d0,u16* d1,u16* d2,u16* d3,u16* d4)
{
  const int g = blockIdx.x * 256 + threadIdx.x;
  if (g >= 10752) return;
  const void* s; u16* d; int base;
  if      (g < 512) { s=s0; d=d0; base=0;    }
  else if (g < 4608){ s=s1; d=d1; base=512;  }
  else if (g < 6656){ s=s2; d=d2; base=4608; }
  else if (g < 8704){ s=s3; d=d3; base=6656; }
  else              { s=s4; d=d4; base=8704; }
  const int i = g - base;
  u64 ov;
  if (*flagp){
    ov = ((const u64*)s)[i];
  } else {
    const float4 f = ((const float4*)s)[i];
    const u16 a0 = f2b(f.x), a1 = f2b(f.y), a2 = f2b(f.z), a3 = f2b(f.w);
    ov = (u64)a0 | ((u64)a1 << 16) | ((u64)a2 << 32) | ((u64)a3 << 48);
  }
  ((u64*)d)[i] = ov;
}

// ---------------------------------------------------------------------------
// 4 3x3-weight reorders in one launch: [co][ci][rs] -> bf16 [co][rs][ci]
// ---------------------------------------------------------------------------
__global__ void k_reorder4(
    const void* w11,const void* w12,const void* w21,const void* w22,
    const int* __restrict__ flagp,
    u16* o11,u16* o12,u16* o21,u16* o22)
{
  int blk = blockIdx.x;
  const void* win; u16* wout; int cin;
  if      (blk < 2304){ win=w11; wout=o11; cin=512; }
  else if (blk < 4608){ win=w12; wout=o12; cin=512; blk-=2304; }
  else if (blk < 5184){ win=w21; wout=o21; cin=128; blk-=4608; }
  else                { win=w22; wout=o22; cin=128; blk-=5184; }
  const int idx = blk * 256 + threadIdx.x;
  const int flg = *flagp;
  const int n9 = cin * 9;
  const int co = idx / n9;
  const int rem = idx - co * n9;
  const int ci = rem / 9;
  const int rs = rem - ci * 9;
  const u16 v = flg ? ((const u16*)win)[idx] : f2b(((const float*)win)[idx]);
  wout[co * n9 + rs * cin + ci] = v;
}

// ---------------------------------------------------------------------------
// Zero halos of the 3 padded tensors in one launch.
// ---------------------------------------------------------------------------
__global__ void k_halo3(u16* __restrict__ xT, u16* __restrict__ f1, u16* __restrict__ cf)
{
  int blk = blockIdx.x;
  u16* buf; int cmask, csh;
  if      (blk < 260){ buf = xT; cmask = 511; csh = 9; }
  else if (blk < 325){ buf = f1; cmask = 127; csh = 7; blk -= 260; }
  else               { buf = cf; cmask = 127; csh = 7; blk -= 325; }
  const int tid = blk * 256 + threadIdx.x;
  const int e  = tid * 8;
  const int cc = e & cmask;
  const int rem = e >> csh;
  const int hp = rem % 260;
  const int b  = rem / 260;
  int pix;
  if      (hp < 66)  pix = hp;
  else if (hp < 132) pix = 65 * 66 + (hp - 66);
  else if (hp < 196) pix = (hp - 132 + 1) * 66;
  else               pix = (hp - 196 + 1) * 66 + 65;
  uint4 z; z.x = 0; z.y = 0; z.z = 0; z.w = 0;
  *(uint4*)(buf + ((size_t)b * PPIX + pix) * (cmask + 1) + cc) = z;
}

// ---------------------------------------------------------------------------
// x transpose: [b][512][4096] (fp32 or bf16) -> padded bf16 [b][4356][512]
// ---------------------------------------------------------------------------
__global__ __launch_bounds__(256) void k_xT(
    const void* __restrict__ src, const int* __restrict__ flagp, u16* __restrict__ dst)
{
  const int t = threadIdx.x, wave = t >> 6, lane = t & 63;
  const int pb = blockIdx.x & 31, ct = (blockIdx.x >> 5) & 7, b = blockIdx.x >> 8;
  const int c  = ct * 64 + lane;
  const int p0 = pb * 128 + wave * 32;
  const size_t sbase = ((size_t)(b * 512) + c) * 4096 + p0;

  u16 vals[32];
  if (*flagp){
    const u16* s = (const u16*)src + sbase;
    #pragma unroll
    for (int k = 0; k < 4; ++k){
      uint4 v = *(const uint4*)(s + k * 8);
      __builtin_memcpy(&vals[k * 8], &v, 16);
    }
  } else {
    const float* s = (const float*)src + sbase;
    #pragma unroll
    for (int k = 0; k < 8; ++k){
      float4 v = *(const float4*)(s + k * 4);
      vals[k*4+0] = f2b(v.x); vals[k*4+1] = f2b(v.y);
      vals[k*4+2] = f2b(v.z); vals[k*4+3] = f2b(v.w);
    }
  }
  const int hrow = (p0 >> 6) * 66 + (p0 & 63) + 67;
  u16* d = dst + ((size_t)b * PPIX + hrow) * 512 + c;
  #pragma unroll
  for (int k = 0; k < 32; ++k) d[(size_t)k * 512] = vals[k];
}

// ---------------------------------------------------------------------------
// Fused sibling 3x3 convs, LDS-tiled implicit GEMM.
// v2: 128co x 64px tiles -> grid 512 = 2 blocks/CU (inter-block overlap
// hides the per-barrier vmcnt drain; R7 had 1 block/CU -> MfmaUtil 18%).
// Wave w: co [ (w>>1)*64, +64 ), px [ (w&1)*32, +32 ): 4x2 frags.
// ---------------------------------------------------------------------------
template<int CIN_, bool PADOUT_, bool DUALB_>
__global__ __launch_bounds__(256) void k_cgemm(
    const u16* __restrict__ xA, const u16* __restrict__ xB,
    const u16* __restrict__ wA, const u16* __restrict__ wB,
    const float* __restrict__ scale, const float* __restrict__ shift,
    u16* __restrict__ outA, u16* __restrict__ outBp, u16* __restrict__ outB2)
{
  constexpr int K9   = 9 * CIN_;
  constexpr int NCH  = CIN_ / 64;
  constexpr int OPIX = PADOUT_ ? PPIX : 4096;

  __shared__ __align__(16) u16 At[128 * 64];   // 16 KB
  __shared__ __align__(16) u16 Bt[64 * 64];    // 8 KB

  const int t = threadIdx.x;
  const int w = t >> 6, lane = t & 63;
  const int l16 = lane & 15, quad = lane >> 4;

  const int cid = blockIdx.x >> 8;           // conv id
  const int rem = blockIdx.x & 255;
  const int b   = rem >> 6;
  const int p0  = (rem & 63) << 6;           // 64-px tile

  const u16* xin = cid ? xB : xA;
  const u16* wK  = cid ? wB : wA;
  const float* sc = scale + cid * 128;
  const float* sh = shift + cid * 128;

  const int rowS = t >> 3;                         // 0..31
  const int sw   = ((t & 7) ^ (rowS & 7)) << 3;    // swizzled global column

  const u16* gA[4]; u16* lA[4];
  #pragma unroll
  for (int k = 0; k < 4; ++k){
    gA[k] = wK + (size_t)(k * 32 + rowS) * K9 + sw;
    lA[k] = At + k * 2048 + w * 512;
  }
  const u16* gB[2]; u16* lB[2];
  #pragma unroll
  for (int k = 0; k < 2; ++k){
    const int px = p0 + k * 32 + rowS;
    const int h = px >> 6, wc = px & 63;
    gB[k] = xin + ((size_t)b * PPIX + h * 66 + wc) * CIN_ + sw;
    lB[k] = Bt + k * 2048 + w * 512;
  }

  f32x4 acc[4][2];
  #pragma unroll
  for (int mi = 0; mi < 4; ++mi)
    #pragma unroll
    for (int ni = 0; ni < 2; ++ni){
      acc[mi][ni][0]=0.f; acc[mi][ni][1]=0.f; acc[mi][ni][2]=0.f; acc[mi][ni][3]=0.f;
    }

  const int wc4 = (w >> 1) << 6;   // wave co base
  const int wp4 = (w & 1) << 5;    // wave px base

  #pragma unroll 1
  for (int tap = 0; tap < 9; ++tap){
    const int tb = (tap / 3) * 66 + (tap % 3);
    #pragma unroll 1
    for (int cc = 0; cc < NCH; ++cc){
      const int offA = tap * CIN_ + cc * 64;
      const int offB = tb  * CIN_ + cc * 64;
      #pragma unroll
      for (int k = 0; k < 4; ++k) gload_lds16(gA[k] + offA, lA[k]);
      #pragma unroll
      for (int k = 0; k < 2; ++k) gload_lds16(gB[k] + offB, lB[k]);
      __syncthreads();
      #pragma unroll
      for (int ks = 0; ks < 2; ++ks){
        bf16x8 af[4], bf[2];
        const int col = ((ks * 4 + quad) ^ (l16 & 7)) << 3;
        #pragma unroll
        for (int mi = 0; mi < 4; ++mi)
          af[mi] = *(const bf16x8*)(At + ((wc4 + mi * 16 + l16) << 6) + col);
        #pragma unroll
        for (int ni = 0; ni < 2; ++ni)
          bf[ni] = *(const bf16x8*)(Bt + ((wp4 + ni * 16 + l16) << 6) + col);
        #pragma unroll
        for (int mi = 0; mi < 4; ++mi)
          #pragma unroll
          for (int ni = 0; ni < 2; ++ni)
            acc[mi][ni] = __builtin_amdgcn_mfma_f32_16x16x32_bf16(af[mi], bf[ni], acc[mi][ni], 0, 0, 0);
      }
      __syncthreads();
    }
  }

  u16* outp = cid ? outBp : outA;
  #pragma unroll
  for (int mi = 0; mi < 4; ++mi){
    #pragma unroll
    for (int ni = 0; ni < 2; ++ni){
      const int px = p0 + wp4 + ni * 16 + l16;
      const int opix = PADOUT_ ? ((px >> 6) * 66 + (px & 63) + 67) : px;
      const int co4 = wc4 + mi * 16 + quad * 4;
      u16 pk[4];
      #pragma unroll
      for (int rr = 0; rr < 4; ++rr)
        pk[rr] = f2b(fmaxf(acc[mi][ni][rr] * sc[co4 + rr] + sh[co4 + rr], 0.f));
      u64 pkv; __builtin_memcpy(&pkv, pk, 8);
      *(u64*)(outp + ((size_t)b * OPIX + opix) * 128 + co4) = pkv;
      if constexpr (DUALB_){
        if (cid){
          #pragma unroll
          for (int rr = 0; rr < 4; ++rr)
            outB2[((size_t)(b * 128) + co4 + rr) * 4096 + px] = pk[rr];
        }
      }
    }
  }
}

// ---------------------------------------------------------------------------
// 1x1 conv (MFMA), one wave per 16(co) x 16(px) tile; pixel-major input.
// EPI: 2 = +bias -> channel-major bf16
//      3 = +bias -> flag ? bf16 : fp32, channel-major (d_out heads)
//      4 = +bias -> qT hi/lo bf16 pair [b][4096][16]
//      6 = CAM: gamma*acc + residual(xin2, padded pixel-major) -> padded pm out
// WPB_: weights indexed per batch (wK + b*CO*K) — used for CAM attn GEMM.
// ---------------------------------------------------------------------------
template<int CIN_, int CO_, int EPI_, bool SUM2_, bool PADIN_, bool PADOUT_, bool WPB_>
__global__ __launch_bounds__(256) void k_convT(
    const u16* __restrict__ xin, const u16* __restrict__ xin2,
    const u16* __restrict__ wK,
    const void* __restrict__ bias, const int* __restrict__ flagp,
    u16* __restrict__ outB, float* __restrict__ outF)
{
  constexpr int K    = CIN_;
  constexpr int MT   = CO_ / 16;
  constexpr int IPIX = PADIN_ ? PPIX : 4096;
  constexpr int OPIX = PADOUT_ ? PPIX : 4096;

  const int tid  = threadIdx.x;
  const int wave = tid >> 6;
  const int lane = tid & 63;
  const int l16  = lane & 15;
  const int quad = lane >> 4;

  int tile = blockIdx.x * 4 + wave;
  const int nt = tile & 255; tile >>= 8;
  const int mt = tile % MT;
  const int b  = tile / MT;

  const int p = nt * 16 + l16;
  const int h = p >> 6, wc = p & 63;

  const u16* wrow = wK + (WPB_ ? (size_t)b * CO_ * K : 0)
                       + (size_t)(mt * 16 + l16) * K + quad * 8;
  const u16* xb   = xin + (size_t)b * IPIX * CIN_ + quad * 8;

  f32x4 acc = {0.f, 0.f, 0.f, 0.f};

  const int poff = PADIN_ ? (h * 66 + wc + 67) : p;
  const u16* xrs = xb + (size_t)poff * CIN_;
  const u16* xrs2 = nullptr;
  if constexpr (SUM2_) xrs2 = xin2 + (size_t)b * IPIX * CIN_ + quad * 8 + (size_t)poff * CIN_;
  #pragma unroll
  for (int ci0 = 0; ci0 < CIN_; ci0 += 32){
    bf16x8 af = *(const bf16x8*)(wrow + ci0);
    bf16x8 bf;
    if constexpr (SUM2_){
      bf16x8 b1 = *(const bf16x8*)(xrs + ci0);
      bf16x8 b2 = *(const bf16x8*)(xrs2 + ci0);
      #pragma unroll
      for (int j = 0; j < 8; ++j)
        bf[j] = (short)f2b(b2f((u16)b1[j]) + b2f((u16)b2[j]));
    } else {
      bf = *(const bf16x8*)(xrs + ci0);
    }
    acc = __builtin_amdgcn_mfma_f32_16x16x32_bf16(af, bf, acc, 0, 0, 0);
  }

  const int flg = *flagp;

  if constexpr (EPI_ == 4){
    #pragma unroll
    for (int rr = 0; rr < 4; ++rr){
      const int co = quad * 4 + rr;   // MT == 1
      const float vv = acc[rr] + ldf(bias, co, flg);
      const u16 hb = f2b(vv);
      const float lo = vv - b2f(hb);
      const size_t qaddr = ((size_t)b * 4096 + p) * 16 + co;
      outB[qaddr] = hb;
      ((u16*)outF)[qaddr] = f2b(lo);
    }
  } else if constexpr (EPI_ == 6){
    const float g = ldf(bias, 0, flg);
    const int opix = PADOUT_ ? (h * 66 + wc + 67) : p;
    const int co4 = mt * 16 + quad * 4;
    const size_t addr = ((size_t)b * OPIX + opix) * CO_ + co4;
    u64 rv = *(const u64*)(xin2 + (size_t)b * OPIX * CO_ + (size_t)opix * CO_ + co4);
    u16 rk[4]; __builtin_memcpy(rk, &rv, 8);
    u16 pk[4];
    #pragma unroll
    for (int rr = 0; rr < 4; ++rr)
      pk[rr] = f2b(g * acc[rr] + b2f(rk[rr]));
    u64 pkv; __builtin_memcpy(&pkv, pk, 8);
    *(u64*)(outB + addr) = pkv;
  } else {
    #pragma unroll
    for (int rr = 0; rr < 4; ++rr){
      const int co = mt * 16 + quad * 4 + rr;
      const float vv = acc[rr] + ldf(bias, co, flg);
      const size_t addr = ((size_t)(b * CO_) + co) * 4096 + p;
      if constexpr (EPI_ == 2) outB[addr] = f2b(vv);
      else { if (flg) outB[addr] = f2b(vv); else outF[addr] = vv; }
    }
  }
}

// ---------------------------------------------------------------------------
// PAM flash attention v3: TWO-PASS (pass A approx row max; pass B stateless
// exp + PV, l via ones-fragment MFMA). F-layout LDS, global_load_lds V.
// Grid 1024 = b x 64 i-tile x 4 j-seg. Block 256 = 4 waves.
// ---------------------------------------------------------------------------
__global__ __launch_bounds__(256) void k_pam_flash(
    const u16* __restrict__ qTh, const u16* __restrict__ qTl,
    const u16* __restrict__ v,
    u16* __restrict__ po, float* __restrict__ pm, float* __restrict__ pl)
{
  __shared__ __align__(16) u16 vls[1024 * 8];   // 16 KB
  __shared__ __align__(16) u16 pls[4][128 * 8]; // 8 KB, per-wave

  const int t    = threadIdx.x;
  const int wave = t >> 6, lane = t & 63;
  const int l16  = lane & 15, quad = lane >> 4;

  const int bid = blockIdx.x;
  const int js  = bid & 3, it = (bid >> 2) & 63, b = bid >> 8;
  const int i0  = it * 64;
  const int jbase = js * 1024;

  const u16* qTbh = qTh + ((size_t)b * 4096) * 16;
  const u16* qTbl = qTl + ((size_t)b * 4096) * 16;
  const u16* vb   = v + ((size_t)b * 128) * 4096;

  bf16x8 af_hl, af_h0 = {};
  {
    const int i = i0 + wave * 16 + l16;
    const u16* src = ((quad < 2) ? qTbh : qTbl) + (size_t)i * 16 + (quad & 1) * 8;
    *(uint4*)&af_hl = *(const uint4*)src;
    if (quad < 2) af_h0 = af_hl;
  }

  // Pass A: segment row max (hi-only QK)
  float mloc[4] = {-3e38f, -3e38f, -3e38f, -3e38f};
  #pragma unroll 1
  for (int ch = 0; ch < 16; ++ch){
    #pragma unroll
    for (int ns = 0; ns < 4; ++ns){
      const int j = jbase + ch * 64 + ns * 16 + l16;
      bf16x8 bh;
      *(uint4*)&bh = *(const uint4*)(qTbh + (size_t)j * 16 + (quad & 1) * 8);
      f32x4 z = {0.f, 0.f, 0.f, 0.f};
      z = __builtin_amdgcn_mfma_f32_16x16x32_bf16(af_hl, bh, z, 0, 0, 0);
      #pragma unroll
      for (int r = 0; r < 4; ++r) mloc[r] = fmaxf(mloc[r], z[r]);
    }
  }
  float mrow[4];
  #pragma unroll
  for (int r = 0; r < 4; ++r){
    float mm = mloc[r];
    mm = fmaxf(mm, __shfl_xor(mm, 1));
    mm = fmaxf(mm, __shfl_xor(mm, 2));
    mm = fmaxf(mm, __shfl_xor(mm, 4));
    mm = fmaxf(mm, __shfl_xor(mm, 8));
    mrow[r] = mm;
  }

  const u16* vsrcB[4];
  u16* vdstB[4];
  #pragma unroll
  for (int k = 0; k < 4; ++k){
    const int p = t + 256 * k;
    const int c  = ((p >> 7) << 4) | (p & 15);
    const int jl = ((p >> 6) & 1) * 32 + ((p >> 4) & 3) * 8;
    vsrcB[k] = vb + (size_t)c * 4096 + jbase + jl;
    vdstB[k] = vls + ((size_t)(wave * 64 + 256 * k)) * 8;
  }

  const short oneb = (short)0x3F80;
  const bf16x8 vones = {oneb,oneb,oneb,oneb,oneb,oneb,oneb,oneb};

  f32x4 oacc[8];
  #pragma unroll
  for (int cs = 0; cs < 8; ++cs){ oacc[cs][0]=0.f; oacc[cs][1]=0.f; oacc[cs][2]=0.f; oacc[cs][3]=0.f; }
  f32x4 lacc = {0.f, 0.f, 0.f, 0.f};

  // Pass B
  #pragma unroll 1
  for (int ch = 0; ch < 16; ++ch){
    const int j0 = ch * 64;
    __syncthreads();
    #pragma unroll
    for (int k = 0; k < 4; ++k)
      gload_lds16(vsrcB[k] + j0, vdstB[k]);

    #pragma unroll
    for (int ns = 0; ns < 4; ++ns){
      const int j = jbase + j0 + ns * 16 + l16;
      bf16x8 bh, bl;
      *(uint4*)&bh = *(const uint4*)(qTbh + (size_t)j * 16 + (quad & 1) * 8);
      *(uint4*)&bl = *(const uint4*)(qTbl + (size_t)j * 16 + (quad & 1) * 8);
      f32x4 z = {0.f, 0.f, 0.f, 0.f};
      z = __builtin_amdgcn_mfma_f32_16x16x32_bf16(af_hl, bh, z, 0, 0, 0);
      z = __builtin_amdgcn_mfma_f32_16x16x32_bf16(af_h0, bl, z, 0, 0, 0);
      const int ks = ns >> 1;
      const int qp = (ns * 2 + (l16 >> 3)) & 3;
      #pragma unroll
      for (int r = 0; r < 4; ++r){
        const float p = __expf(z[r] - mrow[r]);
        pls[wave][(ks * 64 + qp * 16 + quad * 4 + r) * 8 + (l16 & 7)] = f2b_trunc(p);
      }
    }
    __syncthreads();
    #pragma unroll
    for (int ks = 0; ks < 2; ++ks){
      bf16x8 pf = *(const bf16x8*)(pls[wave] + ((ks * 64 + lane) << 3));
      #pragma unroll
      for (int cs = 0; cs < 8; ++cs){
        bf16x8 vf = *(const bf16x8*)(vls + (((cs * 2 + ks) * 64 + lane) << 3));
        oacc[cs] = __builtin_amdgcn_mfma_f32_16x16x32_bf16(pf, vf, oacc[cs], 0, 0, 0);
      }
      lacc = __builtin_amdgcn_mfma_f32_16x16x32_bf16(pf, vones, lacc, 0, 0, 0);
    }
  }

  u16* pob = po + (size_t)bid * 64 * 128;
  #pragma unroll
  for (int cs = 0; cs < 8; ++cs)
    #pragma unroll
    for (int r = 0; r < 4; ++r)
      pob[(wave * 16 + quad * 4 + r) * 128 + cs * 16 + l16] = f2b(oacc[cs][r]);
  if (l16 == 0){
    #pragma unroll
    for (int r = 0; r < 4; ++r){
      pm[(size_t)bid * 64 + wave * 16 + quad * 4 + r] = mrow[r];
      pl[(size_t)bid * 64 + wave * 16 + quad * 4 + r] = lacc[r];
    }
  }
}

// ---------------------------------------------------------------------------
// PAM combine (pixel-major): merge 4 j-seg partials, gamma + residual.
// ---------------------------------------------------------------------------
__global__ __launch_bounds__(256) void k_pam_comb2(
    const u16* __restrict__ po, const float* __restrict__ pm, const float* __restrict__ pl,
    const void* __restrict__ gptr, const int* __restrict__ flagp,
    u16* __restrict__ featT)
{
  __shared__ float wgt[4][64];
  const int t  = threadIdx.x;
  const int it = blockIdx.x & 63, b = blockIdx.x >> 6;
  const int base = (b * 64 + it) * 4;
  if (t < 64){
    const float m0 = pm[(size_t)(base+0)*64 + t];
    const float m1 = pm[(size_t)(base+1)*64 + t];
    const float m2 = pm[(size_t)(base+2)*64 + t];
    const float m3 = pm[(size_t)(base+3)*64 + t];
    const float M  = fmaxf(fmaxf(m0, m1), fmaxf(m2, m3));
    const float e0 = __expf(m0 - M), e1 = __expf(m1 - M);
    const float e2 = __expf(m2 - M), e3 = __expf(m3 - M);
    const float L  = pl[(size_t)(base+0)*64+t]*e0 + pl[(size_t)(base+1)*64+t]*e1
                   + pl[(size_t)(base+2)*64+t]*e2 + pl[(size_t)(base+3)*64+t]*e3;
    const float li = 1.0f / L;
    wgt[0][t] = e0*li; wgt[1][t] = e1*li; wgt[2][t] = e2*li; wgt[3][t] = e3*li;
  }
  __syncthreads();
  const float g = ldf(gptr, 0, *flagp);
  const int c = t & 127, ih = t >> 7;
  const int i0 = it * 64;
  for (int st = 0; st < 32; ++st){
    const int il = ih + st * 2;
    float acc = 0.f;
    #pragma unroll
    for (int s = 0; s < 4; ++s)
      acc += wgt[s][il] * b2f(po[((size_t)(base+s)*64 + il)*128 + c]);
    const int i = i0 + il;
    const int pix = (i >> 6) * 66 + (i & 63) + 67;
    u16* addr = featT + ((size_t)b * PPIX + pix) * 128 + c;
    *addr = f2b(g * acc + b2f(*addr));
  }
}

// ---------------------------------------------------------------------------
// CAM energy + softmax via MFMA. Grid 32 = b(4) x ct(8); block 256.
// ---------------------------------------------------------------------------
__global__ __launch_bounds__(256) void k_cam_energy(
    const u16* __restrict__ f, u16* __restrict__ attnc)
{
  __shared__ float els[16][132];
  const int t = threadIdx.x, wave = t >> 6, lane = t & 63;
  const int l16 = lane & 15, quad = lane >> 4;
  const int ct = blockIdx.x & 7, b = blockIdx.x >> 3;
  const u16* fb = f + (size_t)b * 128 * 4096;
  const int c0 = ct * 16;
  const int d0 = wave * 32;

  f32x4 e0 = {0.f,0.f,0.f,0.f}, e1 = {0.f,0.f,0.f,0.f};
  #pragma unroll 2
  for (int k0 = 0; k0 < 4096; k0 += 32){
    bf16x8 afr, bf0, bf1;
    *(uint4*)&afr = *(const uint4*)(fb + (size_t)(c0 + l16) * 4096 + k0 + quad * 8);
    *(uint4*)&bf0 = *(const uint4*)(fb + (size_t)(d0 + l16) * 4096 + k0 + quad * 8);
    *(uint4*)&bf1 = *(const uint4*)(fb + (size_t)(d0 + 16 + l16) * 4096 + k0 + quad * 8);
    e0 = __builtin_amdgcn_mfma_f32_16x16x32_bf16(afr, bf0, e0, 0, 0, 0);
    e1 = __builtin_amdgcn_mfma_f32_16x16x32_bf16(afr, bf1, e1, 0, 0, 0);
  }
  #pragma unroll
  for (int r = 0; r < 4; ++r){
    els[quad * 4 + r][d0 + l16]      = e0[r];
    els[quad * 4 + r][d0 + 16 + l16] = e1[r];
  }
  __syncthreads();
  const int c = wave * 4 + quad, sg = l16;
  float mn = 3e38f;
  float ev[8];
  #pragma unroll
  for (int k = 0; k < 8; ++k){ ev[k] = els[c][sg * 8 + k]; mn = fminf(mn, ev[k]); }
  mn = fminf(mn, __shfl_xor(mn, 1));
  mn = fminf(mn, __shfl_xor(mn, 2));
  mn = fminf(mn, __shfl_xor(mn, 4));
  mn = fminf(mn, __shfl_xor(mn, 8));
  float s = 0.f;
  #pragma unroll
  for (int k = 0; k < 8; ++k){ ev[k] = __expf(mn - ev[k]); s += ev[k]; }
  s += __shfl_xor(s, 1); s += __shfl_xor(s, 2);
  s += __shfl_xor(s, 4); s += __shfl_xor(s, 8);
  const float inv = 1.0f / s;
  u16* dst = attnc + ((size_t)b * 128 + c0 + c) * 128 + sg * 8;
  #pragma unroll
  for (int k = 0; k < 8; ++k) dst[k] = f2b(ev[k] * inv);
}

// ---------------------------------------------------------------------------
extern "C" void kernel_launch(void* const* d_in, const int* in_sizes, int n_in,
                              void* d_out, int out_size, void* d_ws, size_t ws_size,
                              hipStream_t stream)
{
  (void)in_sizes; (void)n_in; (void)out_size; (void)ws_size;

  const void* x    = d_in[0];
  const void* w11  = d_in[1];
  const void* g11  = d_in[2];
  const void* b11  = d_in[3];
  const void* m11  = d_in[4];
  const void* v11  = d_in[5];
  const void* w12  = d_in[6];
  const void* g12  = d_in[7];
  const void* b12  = d_in[8];
  const void* m12  = d_in[9];
  const void* v12  = d_in[10];
  const void* kw   = d_in[11];
  const void* kb   = d_in[12];
  const void* vw   = d_in[13];
  const void* vb   = d_in[14];
  const void* pgam = d_in[15];
  const void* cgam = d_in[16];
  const void* w21  = d_in[17];
  const void* g21  = d_in[18];
  const void* b21  = d_in[19];
  const void* m21  = d_in[20];
  const void* v21  = d_in[21];
  const void* w22  = d_in[22];
  const void* g22  = d_in[23];
  const void* b22  = d_in[24];
  const void* m22  = d_in[25];
  const void* v22  = d_in[26];
  const void* w31  = d_in[27];
  const void* b31  = d_in[28];
  const void* w32  = d_in[29];
  const void* b32  = d_in[30];
  const void* w4   = d_in[31];
  const void* b4   = d_in[32];

  char* wsb = (char*)d_ws;
  size_t off = 0;
  auto alloc = [&](size_t bytes) -> void* {
    void* pp = wsb + off;
    off += (bytes + 255) & ~(size_t)255;
    return pp;
  };
  u16*   xT      = (u16*)alloc((size_t)4 * PPIX * 512 * 2);  // dead after trunk -> po
  u16*   feat1T  = (u16*)alloc((size_t)4 * PPIX * 128 * 2);  // padded; later pa_feat (in-place)
  u16*   feat2T  = (u16*)alloc((size_t)4 * PPIX * 128 * 2);  // padded (residual reads)
  u16*   feat2cm = (u16*)alloc((size_t)4 * 128 * HW * 2);    // channel-major (CAM energy)
  u16*   cafeatT = (u16*)alloc((size_t)4 * PPIX * 128 * 2);  // padded
  u16*   vbuf    = (u16*)alloc((size_t)4 * 128 * HW * 2);    // v cm; later pa_conv_T (unpadded)
  u16*   caconvT = (u16*)alloc((size_t)4 * HW * 128 * 2);    // unpadded pixel-major
  u16*   qTh     = (u16*)alloc((size_t)4 * HW * 16 * 2);
  u16*   qTl     = (u16*)alloc((size_t)4 * HW * 16 * 2);
  float* pm      = (float*)alloc((size_t)1024 * 64 * 4);
  float* pl      = (float*)alloc((size_t)1024 * 64 * 4);
  u16*   attnc   = (u16*)alloc((size_t)4 * 128 * 128 * 2);
  float* scale   = (float*)alloc(512 * 4);
  float* shift   = (float*)alloc(512 * 4);
  u16*   w11r    = (u16*)alloc((size_t)128 * 4608 * 2);
  u16*   w12r    = (u16*)alloc((size_t)128 * 4608 * 2);
  u16*   w21r    = (u16*)alloc((size_t)128 * 1152 * 2);
  u16*   w22r    = (u16*)alloc((size_t)128 * 1152 * 2);
  u16*   kwb     = (u16*)alloc((size_t)16 * 128 * 2);
  u16*   vwb     = (u16*)alloc((size_t)128 * 128 * 2);
  u16*   w31b    = (u16*)alloc((size_t)64 * 128 * 2);
  u16*   w32b    = (u16*)alloc((size_t)64 * 128 * 2);
  u16*   w4b     = (u16*)alloc((size_t)64 * 128 * 2);
  int*   flag    = (int*)alloc(256);
  u16*   po      = xT;   // 16.8 MB <= xT's 17.8 MB; xT dead after trunk convs

  // prep
  k_prep<<<1, 512, 0, stream>>>((const u32*)x,
                                g11,b11,m11,v11, g12,b12,m12,v12,
                                g21,b21,m21,v21, g22,b22,m22,v22, flag, scale, shift);
  k_halo3<<<390, 256, 0, stream>>>(xT, feat1T, cafeatT);
  k_xT<<<1024, 256, 0, stream>>>(x, flag, xT);
  k_reorder4<<<5760, 256, 0, stream>>>(w11, w12, w21, w22, flag, w11r, w12r, w21r, w22r);
  k_cvt5<<<42, 256, 0, stream>>>(kw, vw, w31, w32, w4, flag, kwb, vwb, w31b, w32b, w4b);

  // trunk convs, fused LDS-GEMM, 2 blocks/CU
  k_cgemm<512, true, true><<<512, 256, 0, stream>>>(
      xT, xT, w11r, w12r, scale, shift, feat1T, feat2T, feat2cm);

  // PAM
  k_convT<128,16,4,false,true,false,false><<<256,256,0,stream>>>(
      feat1T, nullptr, kwb, kb, flag, qTh, (float*)qTl);
  k_convT<128,128,2,false,true,false,false><<<2048,256,0,stream>>>(
      feat1T, nullptr, vwb, vb, flag, vbuf, nullptr);
  k_pam_flash<<<1024, 256, 0, stream>>>(qTh, qTl, vbuf, po, pm, pl);
  k_pam_comb2<<<256, 256, 0, stream>>>(po, pm, pl, pgam, flag, feat1T);  // -> pa_feat

  // CAM: MFMA energy+softmax, then MFMA GEMM attn @ f with residual epilogue
  k_cam_energy<<<32, 256, 0, stream>>>(feat2cm, attnc);
  k_convT<128,128,6,false,true,true,true><<<2048,256,0,stream>>>(
      feat2T, feat2T, attnc, cgam, flag, cafeatT, nullptr);

  // second convs, fused LDS-GEMM, 2 blocks/CU
  k_cgemm<128, false, false><<<512, 256, 0, stream>>>(
      feat1T, cafeatT, w21r, w22r, scale + 256, shift + 256, vbuf, caconvT, nullptr);

  // heads -> d_out [3][4][64][4096], channel-major, dtype per flag
  const size_t SEC = (size_t)4 * 64 * HW;
  u16*   outB = (u16*)d_out;
  float* outF = (float*)d_out;
  k_convT<128,64,3,false,false,false,false><<<1024,256,0,stream>>>(
      vbuf,    nullptr, w31b, b31, flag, outB,           outF);
  k_convT<128,64,3,false,false,false,false><<<1024,256,0,stream>>>(
      caconvT, nullptr, w32b, b32, flag, outB + SEC,     outF + SEC);
  k_convT<128,64,3,true ,false,false,false><<<1024,256,0,stream>>>(
      vbuf,    caconvT, w4b,  b4,  flag, outB + 2 * SEC, outF + 2 * SEC);
}